// Round 4
// baseline (868.634 us; speedup 1.0000x reference)
//
#include <hip/hip_runtime.h>

#define NN 100000
#define NE 600000
#define NF 166
#define NH 128
#define NNH 12800000

enum { EPI_PLAIN = 0, EPI_RELU = 2, EPI_H = 3, EPI_HEAD = 4, EPI_ATTLN = 5 };

typedef short bf16x8 __attribute__((ext_vector_type(8)));
typedef float f32x16 __attribute__((ext_vector_type(16)));
typedef _Float16 f16x2 __attribute__((ext_vector_type(2)));
typedef _Float16 f16x4 __attribute__((ext_vector_type(4)));
typedef _Float16 f16x8 __attribute__((ext_vector_type(8)));

__device__ __forceinline__ unsigned short f2bf(float f) {
  unsigned u = __float_as_uint(f);
  u += 0x7fffu + ((u >> 16) & 1u);
  return (unsigned short)(u >> 16);
}

__device__ __forceinline__ unsigned short f2h(float f) {
  return __builtin_bit_cast(unsigned short, (_Float16)f);
}

// async global->LDS, 16B per lane; LDS dest is wave-uniform base + lane*16
__device__ __forceinline__ void gl_lds16(const void* g, void* l) {
  __builtin_amdgcn_global_load_lds((__attribute__((address_space(1))) void*)(void*)g,
                                   (__attribute__((address_space(3))) void*)l, 16, 0, 0);
}

// ---------------- MFMA GEMM: C[n,m] = epi(sum_k A[n,k]*W[m,k]) -------------
// OUTK : 0 none, 1 f32 C, 2 bf16 Cb, 3 f16 Cb
// CONC : K=256, k>=128 sourced from A2 (concat-K, e.g. [h|mem])
// DUALA: blockIdx.x==1 uses A2 and bias2 (W rows already concatenated)
// F16  : A/W are fp16 (uses f16 MFMA); else bf16
// NT   : number of 32-col tiles per block (M = NT*32*gridDim.x)
template<int EPI, int OUTK, bool BIAS2, bool CONC, bool DUALA, bool F16, int NT>
__launch_bounds__(256)
__global__ void mgemm(const unsigned short* __restrict__ A, int lda,
                      const unsigned short* __restrict__ A2,
                      const unsigned short* __restrict__ W, int ldw,
                      float* __restrict__ C, int ldc,
                      unsigned short* __restrict__ Cb, int ldcb,
                      int K, int M,
                      const float* __restrict__ bias, const float* __restrict__ bias2,
                      const float* __restrict__ wtv, const float* __restrict__ ntv,
                      const float* __restrict__ mem, const int* __restrict__ scal)
{
  __shared__ unsigned short As[128 * 64];
  __shared__ unsigned short Bs[NT * 32 * 64];
  const int tid = threadIdx.x;
  const int wave = tid >> 6, lane = tid & 63;
  const int row0 = blockIdx.y * 128, col0 = blockIdx.x * NT * 32;
  if (DUALA && blockIdx.x) { A = A2; bias = bias2; }
  const int hi = lane >> 5, l5 = lane & 31, l3 = lane & 7;
  f32x16 acc[NT] = {};

  for (int k0 = 0; k0 < K; k0 += 64) {
    const unsigned short* Asrc = A;
    int kk = k0;
    if (CONC && k0 >= 128) { Asrc = A2; kk = k0 - 128; }
    __syncthreads();
#pragma unroll
    for (int q = 0; q < 4; ++q) {
      int id = q * 256 + tid;
      int r = id >> 3, cch = id & 7;
      // source-side XOR swizzle; LDS dest stays linear (required by global_load_lds)
      int sw = ((cch ^ (r & 7)) << 3);
      int gr = row0 + r; if (gr > NN - 1) gr = NN - 1;
      gl_lds16(Asrc + (size_t)gr * lda + kk + sw, &As[(q * 256 + wave * 64) * 8]);
    }
#pragma unroll
    for (int q = 0; q < NT; ++q) {
      int id = q * 256 + tid;
      int r = id >> 3, cch = id & 7;
      int sw = ((cch ^ (r & 7)) << 3);
      int gm = col0 + r; if (gm > M - 1) gm = M - 1;
      gl_lds16(W + (size_t)gm * ldw + k0 + sw, &Bs[(q * 256 + wave * 64) * 8]);
    }
    __syncthreads();   // compiler drains vmcnt before barrier -> LDS data visible
#pragma unroll
    for (int s = 0; s < 4; ++s) {
      int slot8 = (((s * 2 + hi) ^ l3) << 3);
      bf16x8 a = *(const bf16x8*)&As[(wave * 32 + l5) * 64 + slot8];
#pragma unroll
      for (int t = 0; t < NT; ++t) {
        bf16x8 b = *(const bf16x8*)&Bs[(t * 32 + l5) * 64 + slot8];
        if (F16)
          acc[t] = __builtin_amdgcn_mfma_f32_32x32x16_f16(
              __builtin_bit_cast(f16x8, a), __builtin_bit_cast(f16x8, b), acc[t], 0, 0, 0);
        else
          acc[t] = __builtin_amdgcn_mfma_f32_32x32x16_bf16(a, b, acc[t], 0, 0, 0);
      }
    }
  }

  float tmin = 0.f, tmax = 0.f;
  if (EPI == EPI_H) { tmin = __int_as_float(scal[5]); tmax = __int_as_float(scal[6]); }
  float bc[NT], wc[NT], b2c[NT];
#pragma unroll
  for (int t = 0; t < NT; ++t) {
    int gcol = col0 + t * 32 + l5;
    int bcol = DUALA ? (gcol & 127) : gcol;
    bc[t] = bias ? bias[bcol] : 0.f;
    if (BIAS2) bc[t] += bias2[gcol];
    if (EPI == EPI_H)     { bc[t] += bias2[gcol]; wc[t] = wtv[gcol]; }
    if (EPI == EPI_ATTLN) { wc[t] = wtv[gcol]; b2c[t] = bias2[gcol]; }
  }
#pragma unroll
  for (int rg = 0; rg < 16; ++rg) {
    int lr = (rg & 3) + 8 * (rg >> 2) + 4 * hi;
    int grow = row0 + wave * 32 + lr;
    if (grow >= NN) continue;
    float ntn = 0.f;
    if (EPI == EPI_H) {
      ntn = ntv[grow];
      if (tmax > tmin) ntn = (ntn - tmin) / (tmax - tmin + 1e-8f);
    }
    float hv[NT];
#pragma unroll
    for (int t = 0; t < NT; ++t) {
      float v = acc[t][rg] + bc[t];
      if (EPI == EPI_RELU || EPI == EPI_HEAD) v = fmaxf(v, 0.f);
      if (EPI == EPI_H) {
        v += ntn * wc[t];
        v = fmaxf(v, 0.f);
        float mv = mem[(size_t)grow * NH + (col0 + t * 32 + l5)];
        v += mv;
        // side-product: bf16 memory snapshot (replaces conv_mem kernel)
        ((unsigned short*)C)[(size_t)grow * NH + (col0 + t * 32 + l5)] = f2bf(mv);
      }
      hv[t] = v;
    }
    if (EPI == EPI_ATTLN) {
      // attended + residual, then LayerNorm across the row (cols live in 32-lane group)
      const _Float16* h2r = (const _Float16*)mem;
      float s = 0.f;
#pragma unroll
      for (int t = 0; t < NT; ++t) {
        hv[t] += (float)h2r[(size_t)grow * NH + (col0 + t * 32 + l5)];
        s += hv[t];
      }
#pragma unroll
      for (int d = 1; d < 32; d <<= 1) s += __shfl_xor(s, d);
      float mean = s * (1.f / 128.f);
      float var = 0.f;
#pragma unroll
      for (int t = 0; t < NT; ++t) { hv[t] -= mean; var += hv[t] * hv[t]; }
#pragma unroll
      for (int d = 1; d < 32; d <<= 1) var += __shfl_xor(var, d);
      float rstd = rsqrtf(var * (1.f / 128.f) + 1e-5f);
#pragma unroll
      for (int t = 0; t < NT; ++t) hv[t] = hv[t] * rstd * wc[t] + b2c[t];
    }
    if (EPI == EPI_HEAD) {
      // fused classifier head: logits = relu(h)@W2.T + b2  (wtv=W2 [2][64], bias2=b2)
      float p0 = hv[0] * wtv[l5]      + hv[1] * wtv[32 + l5];
      float p1 = hv[0] * wtv[64 + l5] + hv[1] * wtv[96 + l5];
#pragma unroll
      for (int d = 1; d < 32; d <<= 1) { p0 += __shfl_xor(p0, d); p1 += __shfl_xor(p1, d); }
      if (l5 == 0) {
        C[(size_t)grow * 2]     = p0 + bias2[0];
        C[(size_t)grow * 2 + 1] = p1 + bias2[1];
      }
    } else {
#pragma unroll
      for (int t = 0; t < NT; ++t) {
        int gcol = col0 + t * 32 + l5;
        if (OUTK == 1) C[(size_t)grow * ldc + gcol] = hv[t];
        if (OUTK == 2) Cb[(size_t)grow * ldcb + gcol] = f2bf(hv[t]);
        if (OUTK == 3) Cb[(size_t)grow * ldcb + gcol] = f2h(hv[t]);
      }
    }
  }
}

// ---------------- pre-convert kernels --------------------------------------
__global__ void conv_x(const float* __restrict__ x, unsigned short* __restrict__ xb)
{
  int i = blockIdx.x * 256 + threadIdx.x;
  if (i >= NN * 192) return;
  int n = i / 192, c = i - n * 192;
  xb[i] = (c < NF) ? f2bf(x[n * NF + c]) : (unsigned short)0;
}

// wb layout: [0,24576) W_in pad192 | [24576,90112) rz: row m = [W_ih[m]|W_hh[m]] (m<256)
//            [90112,122880) c: rows 0:128=W_ih[256:384], 128:256=W_hh[256:384]
//            [122880,155648) W_gr ++ W_gh | [155648,172032) Wv (unused)
//            [172032,188416) Wo (overwritten by composed f16 W') | [188416,196608) W1
__global__ void conv_w(const float* __restrict__ Wi, const float* __restrict__ Wih,
                       const float* __restrict__ Whh, const float* __restrict__ Wgr,
                       const float* __restrict__ Wgh, const float* __restrict__ Wv,
                       const float* __restrict__ Wo, const float* __restrict__ W1,
                       unsigned short* __restrict__ wb)
{
  int i = blockIdx.x * 256 + threadIdx.x;
  if (i >= 196608) return;
  float v;
  if (i < 24576)       { int r = i / 192, c = i - r * 192; v = (c < NF) ? Wi[r * NF + c] : 0.f; }
  else if (i < 90112)  { int j = i - 24576; int r = j >> 8, c = j & 255;
                         v = (c < 128) ? Wih[r * 128 + c] : Whh[r * 128 + (c - 128)]; }
  else if (i < 122880) { int j = i - 90112; int r = j >> 7, c = j & 127;
                         v = (r < 128) ? Wih[(256 + r) * 128 + c] : Whh[(128 + r) * 128 + c]; }
  else if (i < 139264) v = Wgr[i - 122880];
  else if (i < 155648) v = Wgh[i - 139264];
  else if (i < 172032) v = Wv[i - 155648];
  else if (i < 188416) v = Wo[i - 172032];
  else                 v = W1[i - 188416];
  wb[i] = f2bf(v);
}

// attended = h2 @ (Wo@Wv).T + (Wo@bv + bo): compose f16 W' and f32 b' on device
__global__ void compose_att(const float* __restrict__ Wv, const float* __restrict__ Wo,
                            const float* __restrict__ bv, const float* __restrict__ bo,
                            _Float16* __restrict__ wout, float* __restrict__ bout)
{
  int i = blockIdx.x * 256 + threadIdx.x;
  if (i >= 16384) return;
  int r = i >> 7, c = i & 127;
  float s = 0.f;
  for (int k = 0; k < 128; ++k) s = fmaf(Wo[r * 128 + k], Wv[k * 128 + c], s);
  wout[i] = (_Float16)s;
  if (c == 0) {
    float t = bo[r];
    for (int k = 0; k < 128; ++k) t = fmaf(Wo[r * 128 + k], bv[k], t);
    bout[r] = t;
  }
}

// ---------------- edge statistics ------------------------------------------
// 1024 value-uniform bins (ts ~ U[0,1)): ~586 edges/bin; monotone in t so
// order-statistic selection over bins is exact.
#define NBIN 1024
#define HBLK 256
__device__ __forceinline__ int ts_bin(float t) {
  int b = (int)(t * (float)NBIN);
  return b > NBIN - 1 ? NBIN - 1 : (b < 0 ? 0 : b);
}

// per-edge: ONE scattered global atomic (cnt_all) + one scattered byte store
// (upd row-side); histogram via LDS + coalesced per-block partials (no atomics)
__global__ void edge_count(const int* __restrict__ row, const int* __restrict__ col,
                           const float* __restrict__ ts,
                           int* __restrict__ cnt_all, unsigned char* __restrict__ upd,
                           int* __restrict__ hpart)
{
  __shared__ unsigned hist[NBIN];
  for (int i = threadIdx.x; i < NBIN; i += 256) hist[i] = 0;
  __syncthreads();
  for (int e = blockIdx.x * 256 + threadIdx.x; e < NE; e += 256 * HBLK) {
    int c = col[e];
    float t = ts[e];
    atomicAdd(cnt_all + c, 1);
    upd[row[e]] = 1;
    atomicAdd(&hist[ts_bin(t)], 1u);
  }
  __syncthreads();
  for (int i = threadIdx.x; i < NBIN; i += 256)
    hpart[blockIdx.x * NBIN + i] = (int)hist[i];
}

// reduce partials, find bins containing order stats K1=299999, K2=300000
__global__ void scan_hist(const int* __restrict__ hpart, int* scal)
{
  __shared__ int tot[NBIN];
  int t = threadIdx.x;
  for (int b = t; b < NBIN; b += 256) {
    int s = 0;
    for (int p = 0; p < HBLK; ++p) s += hpart[p * NBIN + b];
    tot[b] = s;
  }
  __syncthreads();
  if (t == 0) {
    const int K1 = 299999, K2 = 300000;
    int run = 0;
    for (int b = 0; b < NBIN; ++b) {
      int c = tot[b];
      if (K1 >= run && K1 < run + c) { scal[0] = b; scal[1] = run; }
      if (K2 >= run && K2 < run + c) { scal[2] = b; scal[3] = run; }
      run += c;
    }
  }
}

#define CAND_CAP 4096
// exact rank-select within candidate bins; med = mean of the two order stats
__global__ void select_med(const float* __restrict__ c1, const float* __restrict__ c2,
                           const int* __restrict__ ccnt, int* scal)
{
  __shared__ float res[2];
  for (int which = 0; which < 2; ++which) {
    const float* c = which ? c2 : c1;
    int m = ccnt[which]; if (m > CAND_CAP) m = CAND_CAP;
    int rank = which ? (300000 - scal[3]) : (299999 - scal[1]);
    for (int i = threadIdx.x; i < m; i += 256) {
      float v = c[i];
      int less = 0, eq = 0;
      for (int j = 0; j < m; ++j) { float w = c[j]; less += (w < v); eq += (w == v); }
      if (less <= rank && rank < less + eq) res[which] = v;
    }
  }
  __syncthreads();
  if (threadIdx.x == 0)
    ((float*)scal)[4] = 0.5f * (res[0] + res[1]);
}

// ---------------- CSR build ------------------------------------------------
__global__ void csr_scan1(const int* __restrict__ cnt, int* loc, int* bsum)
{
  __shared__ int s[256];
  int t = threadIdx.x;
  int i = blockIdx.x * 256 + t;
  int v = (i < NN) ? cnt[i] : 0;
  s[t] = v;
  __syncthreads();
  for (int d = 1; d < 256; d <<= 1) {
    int add = (t >= d) ? s[t - d] : 0;
    __syncthreads();
    s[t] += add;
    __syncthreads();
  }
  if (i < NN) loc[i] = s[t] - v;
  if (t == 255) bsum[blockIdx.x] = s[255];
}

__global__ void csr_scan2(int* bsum, int nb)
{
  if (threadIdx.x == 0) {
    int run = 0;
    for (int i = 0; i < nb; ++i) { int v = bsum[i]; bsum[i] = run; run += v; }
  }
}

__global__ void csr_scan3(const int* __restrict__ loc, const int* __restrict__ bsum,
                          int* off, int* fillpos)
{
  int i = blockIdx.x * 256 + threadIdx.x;
  if (i < NN) {
    int o = loc[i] + bsum[i >> 8];
    off[i] = o;
    fillpos[i] = o;
  }
  if (i == 0) off[NN] = NE;
}

// fill CSR (elist = row id, tsl = timestamp) + median-bin candidate collection
__global__ void csr_fill(const int* __restrict__ row, const int* __restrict__ col,
                         const float* __restrict__ ts, const int* __restrict__ scal,
                         int* fillpos, int* __restrict__ elist, float* __restrict__ tsl,
                         float* cand1, float* cand2, int* ccnt)
{
  int e = blockIdx.x * 256 + threadIdx.x;
  if (e >= NE) return;
  int c = col[e], r = row[e];
  float t = ts[e];
  int slot = atomicAdd(fillpos + c, 1);
  elist[slot] = r;
  tsl[slot] = t;
  int b = ts_bin(t);
  if (b == scal[0]) {
    int s = atomicAdd(ccnt + 0, 1);
    if (s < CAND_CAP) cand1[s] = t;
  }
  if (b == scal[2]) {
    int s = atomicAdd(ccnt + 1, 1);
    if (s < CAND_CAP) cand2[s] = t;
  }
}

// per-node segment scan: nt=max ts, rec bits into elist, cnt_rec -> dis,
// col-side upd, and global nt min/max (replaces node_minmax/node_dis/atomicMax)
__global__ void node_scan(const int* __restrict__ off, int* __restrict__ elist,
                          const float* __restrict__ tsl, const int* __restrict__ scal,
                          float* __restrict__ nt, float* __restrict__ dis_r,
                          float* __restrict__ dis_h, unsigned char* __restrict__ upd,
                          int* scal_mm)
{
  int n = blockIdx.x * 256 + threadIdx.x;
  float mx = 0.f;
  bool valid = n < NN;
  if (valid) {
    int o0 = off[n], o1 = off[n + 1];
    float med = __int_as_float(scal[4]);
    int cr = 0;
    for (int j = o0; j < o1; ++j) {
      float t = tsl[j];
      mx = fmaxf(mx, t);
      if (t >= med) { cr++; elist[j] |= 0x80000000; }
    }
    nt[n] = mx;
    dis_r[n] = rsqrtf((float)cr + 1.f);
    dis_h[n] = rsqrtf((float)(o1 - o0 - cr) + 1.f);
    if (o1 > o0) upd[n] = 1;
  }
  float vmin = valid ? mx : 1e30f;
  float vmax = valid ? mx : -1e30f;
#pragma unroll
  for (int d = 1; d < 64; d <<= 1) {
    vmin = fminf(vmin, __shfl_xor(vmin, d));
    vmax = fmaxf(vmax, __shfl_xor(vmax, d));
  }
  __shared__ float smin[4], smax[4];
  int lane = threadIdx.x & 63, w = threadIdx.x >> 6;
  if (lane == 0) { smin[w] = vmin; smax[w] = vmax; }
  __syncthreads();
  if (threadIdx.x == 0) {
    float a = fminf(fminf(smin[0], smin[1]), fminf(smin[2], smin[3]));
    float b = fmaxf(fmaxf(smax[0], smax[1]), fmaxf(smax[2], smax[3]));
    atomicMin(scal_mm + 5, __float_as_int(a));
    atomicMax(scal_mm + 6, __float_as_int(b));
  }
}

// ---------------- GRU (f16 preacts in, f32 memory out) ---------------------
__device__ __forceinline__ float gru1(float rp, float zp, float ic, float hc, float mv) {
  float r = 1.f / (1.f + expf(-rp));
  float z = 1.f / (1.f + expf(-zp));
  float c = tanhf(ic + r * hc);
  return (1.f - z) * c + z * mv;
}

__global__ void gru_kernel(const _Float16* __restrict__ RZ, const _Float16* __restrict__ ICHC,
                           const float* __restrict__ mem, const unsigned char* __restrict__ upd,
                           float* __restrict__ out)
{
  int idx = blockIdx.x * 256 + threadIdx.x;
  if (idx >= NN * 32) return;
  int n = idx >> 5, q = (idx & 31) << 2;
  size_t p128 = (size_t)n * 128 + q;
  size_t p256 = (size_t)n * 256 + q;
  float4 mv = *(const float4*)(mem + p128);
  float4 o = mv;
  if (upd[n]) {
    f16x4 rp = *(const f16x4*)(RZ + p256);
    f16x4 zp = *(const f16x4*)(RZ + p256 + 128);
    f16x4 ic = *(const f16x4*)(ICHC + p256);
    f16x4 hc = *(const f16x4*)(ICHC + p256 + 128);
    o.x = gru1((float)rp[0], (float)zp[0], (float)ic[0], (float)hc[0], mv.x);
    o.y = gru1((float)rp[1], (float)zp[1], (float)ic[1], (float)hc[1], mv.y);
    o.z = gru1((float)rp[2], (float)zp[2], (float)ic[2], (float)hc[2], mv.z);
    o.w = gru1((float)rp[3], (float)zp[3], (float)ic[3], (float)hc[3], mv.w);
  }
  *(float4*)(out + p128) = o;
}

// ---------------- fused CSR gather + self-loop + softmax + LN --------------
// hl2: f16 [NN,256], cols 0:128 RECENT proj, 128:256 HISTORY proj.
// Wave-uniform control path scalarized; lanes do one 4B half2 load + 2 FMA/edge.
__global__ void gather_combine(const int* __restrict__ off, const int* __restrict__ elist,
                               const float* __restrict__ dis_r, const float* __restrict__ dis_h,
                               const _Float16* __restrict__ hl2,
                               const float* __restrict__ bgr, const float* __restrict__ bgh,
                               const float* __restrict__ g, const float* __restrict__ b,
                               _Float16* __restrict__ h2)
{
  int n = blockIdx.x * 4 + (threadIdx.x >> 6);
  if (n >= NN) return;
  int lane = threadIdx.x & 63;
  int o0 = __builtin_amdgcn_readfirstlane(off[n]);
  int o1 = __builtin_amdgcn_readfirstlane(off[n + 1]);
  float dnr = dis_r[n], dnh = dis_h[n];
  float arx = 0.f, ary = 0.f, ahx = 0.f, ahy = 0.f;
  int j = o0;
  for (; j + 1 < o1; j += 2) {
    int p0 = __builtin_amdgcn_readfirstlane(elist[j]);
    int p1 = __builtin_amdgcn_readfirstlane(elist[j + 1]);
    int r0 = p0 & 0x7fffffff, r1 = p1 & 0x7fffffff;
    int c0 = ((unsigned)p0) >> 31, c1 = ((unsigned)p1) >> 31;
    float d0 = c0 ? dis_r[r0] : dis_h[r0];
    float d1 = c1 ? dis_r[r1] : dis_h[r1];
    f16x2 v0 = *(const f16x2*)(hl2 + (size_t)r0 * 256 + ((c0 ^ 1) << 7) + (lane << 1));
    f16x2 v1 = *(const f16x2*)(hl2 + (size_t)r1 * 256 + ((c1 ^ 1) << 7) + (lane << 1));
    float k0 = d0 * (c0 ? dnr : dnh);
    float k1 = d1 * (c1 ? dnr : dnh);
    if (c0) { arx = fmaf(k0, (float)v0[0], arx); ary = fmaf(k0, (float)v0[1], ary); }
    else    { ahx = fmaf(k0, (float)v0[0], ahx); ahy = fmaf(k0, (float)v0[1], ahy); }
    if (c1) { arx = fmaf(k1, (float)v1[0], arx); ary = fmaf(k1, (float)v1[1], ary); }
    else    { ahx = fmaf(k1, (float)v1[0], ahx); ahy = fmaf(k1, (float)v1[1], ahy); }
  }
  if (j < o1) {
    int p0 = __builtin_amdgcn_readfirstlane(elist[j]);
    int r0 = p0 & 0x7fffffff;
    int c0 = ((unsigned)p0) >> 31;
    float d0 = c0 ? dis_r[r0] : dis_h[r0];
    f16x2 v0 = *(const f16x2*)(hl2 + (size_t)r0 * 256 + ((c0 ^ 1) << 7) + (lane << 1));
    float k0 = d0 * (c0 ? dnr : dnh);
    if (c0) { arx = fmaf(k0, (float)v0[0], arx); ary = fmaf(k0, (float)v0[1], ary); }
    else    { ahx = fmaf(k0, (float)v0[0], ahx); ahy = fmaf(k0, (float)v0[1], ahy); }
  }
  // self-loop + bias
  f16x2 lr = *(const f16x2*)(hl2 + (size_t)n * 256 + (lane << 1));
  f16x2 lh = *(const f16x2*)(hl2 + (size_t)n * 256 + 128 + (lane << 1));
  float2 br = *(const float2*)(bgr + (lane << 1));
  float2 bh = *(const float2*)(bgh + (lane << 1));
  float rx = arx + (float)lr[0] * dnr * dnr + br.x;
  float ry = ary + (float)lr[1] * dnr * dnr + br.y;
  float hx = ahx + (float)lh[0] * dnh * dnh + bh.x;
  float hy = ahy + (float)lh[1] * dnh * dnh + bh.y;
  // path softmax over per-path means
  float sa = rx + ry, sc = hx + hy;
#pragma unroll
  for (int d = 1; d < 64; d <<= 1) { sa += __shfl_xor(sa, d); sc += __shfl_xor(sc, d); }
  float m0 = sa * (1.f / 128.f), m1 = sc * (1.f / 128.f);
  float mx = fmaxf(m0, m1);
  float e0 = expf(m0 - mx), e1 = expf(m1 - mx);
  float inv = 1.f / (e0 + e1);
  float w0 = e0 * inv, w1 = e1 * inv;
  float yx = w0 * rx + w1 * hx;
  float yy = w0 * ry + w1 * hy;
  // LayerNorm
  float s = yx + yy;
#pragma unroll
  for (int d = 1; d < 64; d <<= 1) s += __shfl_xor(s, d);
  float mean = s * (1.f / 128.f);
  float dx = yx - mean, dy = yy - mean;
  float vv = dx * dx + dy * dy;
#pragma unroll
  for (int d = 1; d < 64; d <<= 1) vv += __shfl_xor(vv, d);
  float rstd = rsqrtf(vv * (1.f / 128.f) + 1e-5f);
  float2 gg = *(const float2*)(g + (lane << 1));
  float2 bb = *(const float2*)(b + (lane << 1));
  f16x2 o;
  o[0] = (_Float16)(dx * rstd * gg.x + bb.x);
  o[1] = (_Float16)(dy * rstd * gg.y + bb.y);
  *(f16x2*)(h2 + (size_t)n * NH + (lane << 1)) = o;
}

extern "C" void kernel_launch(void* const* d_in, const int* in_sizes, int n_in,
                              void* d_out, int out_size, void* d_ws, size_t ws_size,
                              hipStream_t stream)
{
  const float* x      = (const float*)d_in[0];
  const int*   ei     = (const int*)  d_in[1];
  const float* ts     = (const float*)d_in[2];
  const float* mem    = (const float*)d_in[3];
  const float* W_in   = (const float*)d_in[4];
  const float* b_in   = (const float*)d_in[5];
  const float* W_time = (const float*)d_in[6];
  const float* b_time = (const float*)d_in[7];
  const float* W_ih   = (const float*)d_in[8];
  const float* W_hh   = (const float*)d_in[9];
  const float* b_ih   = (const float*)d_in[10];
  const float* b_hh   = (const float*)d_in[11];
  const float* W_gr   = (const float*)d_in[12];
  const float* b_gr   = (const float*)d_in[13];
  const float* W_gh   = (const float*)d_in[14];
  const float* b_gh   = (const float*)d_in[15];
  const float* ln_pa_g= (const float*)d_in[16];
  const float* ln_pa_b= (const float*)d_in[17];
  const float* Wv     = (const float*)d_in[18];
  const float* bv     = (const float*)d_in[19];
  const float* Wo     = (const float*)d_in[20];
  const float* bo     = (const float*)d_in[21];
  const float* ln_at_g= (const float*)d_in[22];
  const float* ln_at_b= (const float*)d_in[23];
  const float* W1     = (const float*)d_in[24];
  const float* b1     = (const float*)d_in[25];
  const float* W2     = (const float*)d_in[26];
  const float* b2     = (const float*)d_in[27];

  const int* row = ei;
  const int* col = ei + NE;
  float* out_logits = (float*)d_out;
  float* out_mem    = (float*)d_out + NN * 2;

  float* ws = (float*)d_ws;
  // ---- workspace layout (offsets in floats), time-multiplexed ----
  // [0, 6.4M)      hb bf16 [NN,128]; after hl2-GEMM dead -> h2 f16 [NN,128]
  // [6.4M, 16M)    xb bf16 [NN,192]  (dead after EPI_H GEMM)
  // [6.4M, 19.2M)  rz f16 [NN,256]   (written after xb dead; dead after gru)
  // [6.4M, 12.8M)  rb bf16 [NN,128]  (written by ATTLN, after rz dead)
  // [19.2M, 32M)   ichc f16 [NN,256] (dead after gru)
  // [32M, 44.8M)   hl2 f16 [NN,256]  (written after gru)
  // [44.8M, 51.2M) memb bf16 [NN,128]
  unsigned short* hb   = (unsigned short*)(ws);
  _Float16* h2         = (_Float16*)(ws);
  unsigned short* xb   = (unsigned short*)(ws + 6400000);
  _Float16* rz         = (_Float16*)(ws + 6400000);
  unsigned short* rb   = (unsigned short*)(ws + 6400000);
  _Float16* ichc       = (_Float16*)(ws + 19200000);
  _Float16* hl2        = (_Float16*)(ws + 32000000);
  unsigned short* memb = (unsigned short*)(ws + 44800000);
  unsigned short* wb   = (unsigned short*)(ws + 51200000);   // 196608 shorts
  float* nt            = ws + 51350000;
  float* dis_r         = ws + 51450000;
  float* dis_h         = ws + 51550000;
  int* cnt_all         = (int*)(ws + 51650000);
  unsigned char* upd   = (unsigned char*)(ws + 51850000);    // NN bytes
  int* scal            = (int*)(ws + 51950000);
  float* batt          = ws + 51960000;
  float* cand1         = ws + 51970000;
  float* cand2         = ws + 51980000;
  int* ccnt            = (int*)(ws + 51990000);
  int* off             = (int*)(ws + 52100000);
  int* fillpos         = (int*)(ws + 52250000);
  int* loc             = (int*)(ws + 52400000);
  int* bsum            = (int*)(ws + 52550000);
  int* elist           = (int*)(ws + 52600000);              // [52.6M, 53.2M)
  float* tsl           = ws + 53200000;                      // [53.2M, 53.8M)
  int* hpart           = (int*)(ws + 53800000);              // 256*1024 ints

  unsigned short* wb_in = wb;
  unsigned short* wb_rz = wb + 24576;    // [256,256] = [W_ih[0:256] | W_hh[0:256]]
  unsigned short* wb_c  = wb + 90112;    // [256,128] = W_ih[256:384] ++ W_hh[256:384]
  unsigned short* wb_gr = wb + 122880;   // [256,128] = W_gr ++ W_gh contiguous
  unsigned short* wb_o  = wb + 172032;   // composed f16 W' = Wo@Wv
  unsigned short* wb_1  = wb + 188416;

  hipMemsetAsync(cnt_all, 0, NN * 4, stream);
  hipMemsetAsync(upd,     0, NN, stream);
  hipMemsetAsync(scal,    0, 16 * 4, stream);
  hipMemsetAsync(scal + 5,0x7f, 4, stream);
  hipMemsetAsync(ccnt,    0, 8, stream);

  const int eb  = (NE + 255) / 256;
  const int nb  = (NN + 255) / 256;
  dim3 blk(256);
  const unsigned gy = (NN + 127) / 128;

  // ---- edge statistics + CSR (atomic-minimized) ----
  edge_count<<<HBLK, 256, 0, stream>>>(row, col, ts, cnt_all, upd, hpart);
  scan_hist <<<1, 256, 0, stream>>>(hpart, scal);
  csr_scan1 <<<nb, 256, 0, stream>>>(cnt_all, loc, bsum);
  csr_scan2 <<<1, 64, 0, stream>>>(bsum, nb);
  csr_scan3 <<<nb, 256, 0, stream>>>(loc, bsum, off, fillpos);
  csr_fill  <<<eb, 256, 0, stream>>>(row, col, ts, scal, fillpos, elist, tsl,
                                     cand1, cand2, ccnt);
  select_med<<<1, 256, 0, stream>>>(cand1, cand2, ccnt, scal);
  node_scan <<<nb, 256, 0, stream>>>(off, elist, tsl, scal, nt, dis_r, dis_h,
                                     upd, scal);

  // bf16 conversions + attention weight composition
  conv_w     <<<768, 256, 0, stream>>>(W_in, W_ih, W_hh, W_gr, W_gh, Wv, Wo, W1, wb);
  compose_att<<<64, 256, 0, stream>>>(Wv, Wo, bv, bo, (_Float16*)wb_o, batt);
  conv_x     <<<75000, 256, 0, stream>>>(x, xb);

  // h = relu(x@W_in.T + b_in + nt_norm*W_time + b_time) + mem (bf16 hb),
  // side-writes memb = bf16(mem)
  mgemm<EPI_H, 2, false, false, false, false, 4><<<dim3(1, gy), blk, 0, stream>>>(
      xb, 192, nullptr, wb_in, 192, (float*)memb, 0, hb, NH, 192, 128,
      b_in, b_time, W_time, nt, mem, scal);
  // r,z preacts (f16): [h|mem] @ [W_ih[0:256]|W_hh[0:256]].T, 256 cols in one block
  mgemm<EPI_PLAIN, 3, true, true, false, false, 8><<<dim3(1, gy), blk, 0, stream>>>(
      hb, NH, memb, wb_rz, 256, nullptr, 0, (unsigned short*)rz, 256, 256, 256,
      b_ih, b_hh, nullptr, nullptr, nullptr, nullptr);
  // ic (x-block 0, A=h) and hc (x-block 1, A=mem) in one dual-A GEMM (f16 out)
  mgemm<EPI_PLAIN, 3, false, false, true, false, 4><<<dim3(2, gy), blk, 0, stream>>>(
      hb, NH, memb, wb_c, NH, nullptr, 0, (unsigned short*)ichc, 256, 128, 256,
      b_ih + 256, b_hh + 256, nullptr, nullptr, nullptr, nullptr);
  gru_kernel<<<(NN * 32) / 256, 256, 0, stream>>>(rz, ichc, mem, upd, out_mem);

  // both GCN projections in one GEMM: hl2 = h @ [W_gr; W_gh].T  [NN,256] f16
  mgemm<EPI_PLAIN, 3, false, false, false, false, 8><<<dim3(1, gy), blk, 0, stream>>>(
      hb, NH, nullptr, wb_gr, NH, nullptr, 0, (unsigned short*)hl2, 256, 128, 256,
      nullptr, nullptr, nullptr, nullptr, nullptr, nullptr);

  // fused gather + self-loop + path softmax + LN -> h2 (f16, aliases dead hb)
  gather_combine<<<(NN + 3) / 4, 256, 0, stream>>>(off, elist, dis_r, dis_h, hl2,
      b_gr, b_gh, ln_pa_g, ln_pa_b, h2);

  // attention + residual + LN fused into one f16 GEMM epilogue -> rb (bf16)
  mgemm<EPI_ATTLN, 2, false, false, false, true, 4><<<dim3(1, gy), blk, 0, stream>>>(
      (const unsigned short*)h2, NH, nullptr, wb_o, NH, nullptr, 0, rb, NH, 128, 128,
      batt, ln_at_b, ln_at_g, nullptr, (const float*)h2, scal);

  // classifier: relu(rb@W1.T+b1)@W2.T+b2 fused into one GEMM epilogue
  mgemm<EPI_HEAD, 0, false, false, false, false, 2><<<dim3(1, gy), blk, 0, stream>>>(
      rb, NH, nullptr, wb_1, NH, out_logits, 0, nullptr, 0, 128, 64,
      b1, b2, W2, nullptr, nullptr, nullptr);

  (void)in_sizes; (void)n_in; (void)out_size; (void)ws_size;
}

// Round 5
// 745.903 us; speedup vs baseline: 1.1645x; 1.1645x over previous
//
#include <hip/hip_runtime.h>

#define NN 100000
#define NE 600000
#define NF 166
#define NH 128
#define NNH 12800000

enum { EPI_PLAIN = 0, EPI_RELU = 2, EPI_H = 3, EPI_HEAD = 4, EPI_ATTLN = 5 };

typedef short bf16x8 __attribute__((ext_vector_type(8)));
typedef float f32x16 __attribute__((ext_vector_type(16)));
typedef _Float16 f16x2 __attribute__((ext_vector_type(2)));
typedef _Float16 f16x4 __attribute__((ext_vector_type(4)));
typedef _Float16 f16x8 __attribute__((ext_vector_type(8)));

__device__ __forceinline__ unsigned short f2bf(float f) {
  unsigned u = __float_as_uint(f);
  u += 0x7fffu + ((u >> 16) & 1u);
  return (unsigned short)(u >> 16);
}

__device__ __forceinline__ unsigned short f2h(float f) {
  return __builtin_bit_cast(unsigned short, (_Float16)f);
}

// async global->LDS, 16B per lane; LDS dest is wave-uniform base + lane*16
__device__ __forceinline__ void gl_lds16(const void* g, void* l) {
  __builtin_amdgcn_global_load_lds((__attribute__((address_space(1))) void*)(void*)g,
                                   (__attribute__((address_space(3))) void*)l, 16, 0, 0);
}

// ---------------- MFMA GEMM: C[n,m] = epi(sum_k A[n,k]*W[m,k]) -------------
// OUTK : 0 none, 1 f32 C, 2 bf16 Cb, 3 f16 Cb
// CONC : K=256, k>=128 sourced from A2 (concat-K, e.g. [h|mem])
// DUALA: blockIdx.x==1 uses A2 and bias2 (W rows already concatenated)
// F16  : A/W are fp16 (uses f16 MFMA); else bf16
// NT   : number of 32-col tiles per block (M = NT*32*gridDim.x)
template<int EPI, int OUTK, bool BIAS2, bool CONC, bool DUALA, bool F16, int NT>
__launch_bounds__(256)
__global__ void mgemm(const unsigned short* __restrict__ A, int lda,
                      const unsigned short* __restrict__ A2,
                      const unsigned short* __restrict__ W, int ldw,
                      float* __restrict__ C, int ldc,
                      unsigned short* __restrict__ Cb, int ldcb,
                      int K, int M,
                      const float* __restrict__ bias, const float* __restrict__ bias2,
                      const float* __restrict__ wtv, const float* __restrict__ ntv,
                      const float* __restrict__ mem, const int* __restrict__ scal)
{
  __shared__ unsigned short As[128 * 64];
  __shared__ unsigned short Bs[NT * 32 * 64];
  const int tid = threadIdx.x;
  const int wave = tid >> 6, lane = tid & 63;
  const int row0 = blockIdx.y * 128, col0 = blockIdx.x * NT * 32;
  if (DUALA && blockIdx.x) { A = A2; bias = bias2; }
  const int hi = lane >> 5, l5 = lane & 31, l3 = lane & 7;
  f32x16 acc[NT] = {};

  for (int k0 = 0; k0 < K; k0 += 64) {
    const unsigned short* Asrc = A;
    int kk = k0;
    if (CONC && k0 >= 128) { Asrc = A2; kk = k0 - 128; }
    __syncthreads();
#pragma unroll
    for (int q = 0; q < 4; ++q) {
      int id = q * 256 + tid;
      int r = id >> 3, cch = id & 7;
      // source-side XOR swizzle; LDS dest stays linear (required by global_load_lds)
      int sw = ((cch ^ (r & 7)) << 3);
      int gr = row0 + r; if (gr > NN - 1) gr = NN - 1;
      gl_lds16(Asrc + (size_t)gr * lda + kk + sw, &As[(q * 256 + wave * 64) * 8]);
    }
#pragma unroll
    for (int q = 0; q < NT; ++q) {
      int id = q * 256 + tid;
      int r = id >> 3, cch = id & 7;
      int sw = ((cch ^ (r & 7)) << 3);
      int gm = col0 + r; if (gm > M - 1) gm = M - 1;
      gl_lds16(W + (size_t)gm * ldw + k0 + sw, &Bs[(q * 256 + wave * 64) * 8]);
    }
    __syncthreads();   // compiler drains vmcnt before barrier -> LDS data visible
#pragma unroll
    for (int s = 0; s < 4; ++s) {
      int slot8 = (((s * 2 + hi) ^ l3) << 3);
      bf16x8 a = *(const bf16x8*)&As[(wave * 32 + l5) * 64 + slot8];
#pragma unroll
      for (int t = 0; t < NT; ++t) {
        bf16x8 b = *(const bf16x8*)&Bs[(t * 32 + l5) * 64 + slot8];
        if (F16)
          acc[t] = __builtin_amdgcn_mfma_f32_32x32x16_f16(
              __builtin_bit_cast(f16x8, a), __builtin_bit_cast(f16x8, b), acc[t], 0, 0, 0);
        else
          acc[t] = __builtin_amdgcn_mfma_f32_32x32x16_bf16(a, b, acc[t], 0, 0, 0);
      }
    }
  }

  float tmin = 0.f, tmax = 0.f;
  if (EPI == EPI_H) { tmin = __int_as_float(scal[5]); tmax = __int_as_float(scal[6]); }
  float bc[NT], wc[NT], b2c[NT];
#pragma unroll
  for (int t = 0; t < NT; ++t) {
    int gcol = col0 + t * 32 + l5;
    int bcol = DUALA ? (gcol & 127) : gcol;
    bc[t] = bias ? bias[bcol] : 0.f;
    if (BIAS2) bc[t] += bias2[gcol];
    if (EPI == EPI_H)     { bc[t] += bias2[gcol]; wc[t] = wtv[gcol]; }
    if (EPI == EPI_ATTLN) { wc[t] = wtv[gcol]; b2c[t] = bias2[gcol]; }
  }
#pragma unroll
  for (int rg = 0; rg < 16; ++rg) {
    int lr = (rg & 3) + 8 * (rg >> 2) + 4 * hi;
    int grow = row0 + wave * 32 + lr;
    if (grow >= NN) continue;
    float ntn = 0.f;
    if (EPI == EPI_H) {
      ntn = ntv[grow];
      if (tmax > tmin) ntn = (ntn - tmin) / (tmax - tmin + 1e-8f);
    }
    float hv[NT];
#pragma unroll
    for (int t = 0; t < NT; ++t) {
      float v = acc[t][rg] + bc[t];
      if (EPI == EPI_RELU || EPI == EPI_HEAD) v = fmaxf(v, 0.f);
      if (EPI == EPI_H) {
        v += ntn * wc[t];
        v = fmaxf(v, 0.f);
        float mv = mem[(size_t)grow * NH + (col0 + t * 32 + l5)];
        v += mv;
        // side-product: bf16 memory snapshot (replaces conv_mem kernel)
        ((unsigned short*)C)[(size_t)grow * NH + (col0 + t * 32 + l5)] = f2bf(mv);
      }
      hv[t] = v;
    }
    if (EPI == EPI_ATTLN) {
      // attended + residual, then LayerNorm across the row (cols live in 32-lane group)
      const _Float16* h2r = (const _Float16*)mem;
      float s = 0.f;
#pragma unroll
      for (int t = 0; t < NT; ++t) {
        hv[t] += (float)h2r[(size_t)grow * NH + (col0 + t * 32 + l5)];
        s += hv[t];
      }
#pragma unroll
      for (int d = 1; d < 32; d <<= 1) s += __shfl_xor(s, d);
      float mean = s * (1.f / 128.f);
      float var = 0.f;
#pragma unroll
      for (int t = 0; t < NT; ++t) { hv[t] -= mean; var += hv[t] * hv[t]; }
#pragma unroll
      for (int d = 1; d < 32; d <<= 1) var += __shfl_xor(var, d);
      float rstd = rsqrtf(var * (1.f / 128.f) + 1e-5f);
#pragma unroll
      for (int t = 0; t < NT; ++t) hv[t] = hv[t] * rstd * wc[t] + b2c[t];
    }
    if (EPI == EPI_HEAD) {
      // fused classifier head: logits = relu(h)@W2.T + b2  (wtv=W2 [2][64], bias2=b2)
      float p0 = hv[0] * wtv[l5]      + hv[1] * wtv[32 + l5];
      float p1 = hv[0] * wtv[64 + l5] + hv[1] * wtv[96 + l5];
#pragma unroll
      for (int d = 1; d < 32; d <<= 1) { p0 += __shfl_xor(p0, d); p1 += __shfl_xor(p1, d); }
      if (l5 == 0) {
        C[(size_t)grow * 2]     = p0 + bias2[0];
        C[(size_t)grow * 2 + 1] = p1 + bias2[1];
      }
    } else {
#pragma unroll
      for (int t = 0; t < NT; ++t) {
        int gcol = col0 + t * 32 + l5;
        if (OUTK == 1) C[(size_t)grow * ldc + gcol] = hv[t];
        if (OUTK == 2) Cb[(size_t)grow * ldcb + gcol] = f2bf(hv[t]);
        if (OUTK == 3) Cb[(size_t)grow * ldcb + gcol] = f2h(hv[t]);
      }
    }
  }
}

// ---------------- pre-convert kernels --------------------------------------
__global__ void conv_x(const float* __restrict__ x, unsigned short* __restrict__ xb)
{
  int i = blockIdx.x * 256 + threadIdx.x;
  if (i >= NN * 192) return;
  int n = i / 192, c = i - n * 192;
  xb[i] = (c < NF) ? f2bf(x[n * NF + c]) : (unsigned short)0;
}

// wb layout: [0,24576) W_in pad192 | [24576,90112) rz: row m = [W_ih[m]|W_hh[m]] (m<256)
//            [90112,122880) c: rows 0:128=W_ih[256:384], 128:256=W_hh[256:384]
//            [122880,155648) W_gr ++ W_gh | [155648,172032) Wv (unused)
//            [172032,188416) Wo (overwritten by composed f16 W') | [188416,196608) W1
__global__ void conv_w(const float* __restrict__ Wi, const float* __restrict__ Wih,
                       const float* __restrict__ Whh, const float* __restrict__ Wgr,
                       const float* __restrict__ Wgh, const float* __restrict__ Wv,
                       const float* __restrict__ Wo, const float* __restrict__ W1,
                       unsigned short* __restrict__ wb)
{
  int i = blockIdx.x * 256 + threadIdx.x;
  if (i >= 196608) return;
  float v;
  if (i < 24576)       { int r = i / 192, c = i - r * 192; v = (c < NF) ? Wi[r * NF + c] : 0.f; }
  else if (i < 90112)  { int j = i - 24576; int r = j >> 8, c = j & 255;
                         v = (c < 128) ? Wih[r * 128 + c] : Whh[r * 128 + (c - 128)]; }
  else if (i < 122880) { int j = i - 90112; int r = j >> 7, c = j & 127;
                         v = (r < 128) ? Wih[(256 + r) * 128 + c] : Whh[(128 + r) * 128 + c]; }
  else if (i < 139264) v = Wgr[i - 122880];
  else if (i < 155648) v = Wgh[i - 139264];
  else if (i < 172032) v = Wv[i - 155648];
  else if (i < 188416) v = Wo[i - 172032];
  else                 v = W1[i - 188416];
  wb[i] = f2bf(v);
}

// attended = h2 @ (Wo@Wv).T + (Wo@bv + bo): compose f16 W' and f32 b' on device
__global__ void compose_att(const float* __restrict__ Wv, const float* __restrict__ Wo,
                            const float* __restrict__ bv, const float* __restrict__ bo,
                            _Float16* __restrict__ wout, float* __restrict__ bout)
{
  int i = blockIdx.x * 256 + threadIdx.x;
  if (i >= 16384) return;
  int r = i >> 7, c = i & 127;
  float s = 0.f;
  for (int k = 0; k < 128; ++k) s = fmaf(Wo[r * 128 + k], Wv[k * 128 + c], s);
  wout[i] = (_Float16)s;
  if (c == 0) {
    float t = bo[r];
    for (int k = 0; k < 128; ++k) t = fmaf(Wo[r * 128 + k], bv[k], t);
    bout[r] = t;
  }
}

// ---------------- edge statistics ------------------------------------------
// 1024 value-uniform bins (ts ~ U[0,1)): ~586 edges/bin; monotone in t so
// order-statistic selection over bins is exact.
#define NBIN 1024
#define HBLK 256
__device__ __forceinline__ int ts_bin(float t) {
  int b = (int)(t * (float)NBIN);
  return b > NBIN - 1 ? NBIN - 1 : (b < 0 ? 0 : b);
}

// per-edge: ONE scattered global atomic (cnt_all) + one scattered byte store
// (upd row-side); LDS histogram flushed via global atomicAdd to ghist[1024]
// (262K atomics over 1024 addrs -- cheap; the 1MB-partials variant made the
// single-block reducer a 121us latency-bound serial kernel)
__global__ void edge_count(const int* __restrict__ row, const int* __restrict__ col,
                           const float* __restrict__ ts,
                           int* __restrict__ cnt_all, unsigned char* __restrict__ upd,
                           int* __restrict__ ghist)
{
  __shared__ unsigned hist[NBIN];
  for (int i = threadIdx.x; i < NBIN; i += 256) hist[i] = 0;
  __syncthreads();
  for (int e = blockIdx.x * 256 + threadIdx.x; e < NE; e += 256 * HBLK) {
    int c = col[e];
    float t = ts[e];
    atomicAdd(cnt_all + c, 1);
    upd[row[e]] = 1;
    atomicAdd(&hist[ts_bin(t)], 1u);
  }
  __syncthreads();
  for (int i = threadIdx.x; i < NBIN; i += 256)
    atomicAdd(ghist + i, (int)hist[i]);
}

// tiny: 4KB read, 256-thread scan; find bins of order stats K1/K2
__global__ void scan_hist(const int* __restrict__ ghist, int* scal)
{
  __shared__ int s[256];
  int t = threadIdx.x;
  int4 mine = *(const int4*)(ghist + t * 4);   // 4 consecutive bins per thread
  int sum4 = mine.x + mine.y + mine.z + mine.w;
  s[t] = sum4;
  __syncthreads();
  for (int d = 1; d < 256; d <<= 1) {
    int add = (t >= d) ? s[t - d] : 0;
    __syncthreads();
    s[t] += add;
    __syncthreads();
  }
  int run = s[t] - sum4;
  const int K1 = 299999, K2 = 300000;
  int c[4] = { mine.x, mine.y, mine.z, mine.w };
#pragma unroll
  for (int k = 0; k < 4; ++k) {
    if (K1 >= run && K1 < run + c[k]) { scal[0] = t * 4 + k; scal[1] = run; }
    if (K2 >= run && K2 < run + c[k]) { scal[2] = t * 4 + k; scal[3] = run; }
    run += c[k];
  }
}

#define CAND_CAP 4096
// exact rank-select within candidate bins; med = mean of the two order stats
__global__ void select_med(const float* __restrict__ c1, const float* __restrict__ c2,
                           const int* __restrict__ ccnt, int* scal)
{
  __shared__ float res[2];
  for (int which = 0; which < 2; ++which) {
    const float* c = which ? c2 : c1;
    int m = ccnt[which]; if (m > CAND_CAP) m = CAND_CAP;
    int rank = which ? (300000 - scal[3]) : (299999 - scal[1]);
    for (int i = threadIdx.x; i < m; i += 256) {
      float v = c[i];
      int less = 0, eq = 0;
      for (int j = 0; j < m; ++j) { float w = c[j]; less += (w < v); eq += (w == v); }
      if (less <= rank && rank < less + eq) res[which] = v;
    }
  }
  __syncthreads();
  if (threadIdx.x == 0)
    ((float*)scal)[4] = 0.5f * (res[0] + res[1]);
}

// ---------------- CSR build ------------------------------------------------
__global__ void csr_scan1(const int* __restrict__ cnt, int* loc, int* bsum)
{
  __shared__ int s[256];
  int t = threadIdx.x;
  int i = blockIdx.x * 256 + t;
  int v = (i < NN) ? cnt[i] : 0;
  s[t] = v;
  __syncthreads();
  for (int d = 1; d < 256; d <<= 1) {
    int add = (t >= d) ? s[t - d] : 0;
    __syncthreads();
    s[t] += add;
    __syncthreads();
  }
  if (i < NN) loc[i] = s[t] - v;
  if (t == 255) bsum[blockIdx.x] = s[255];
}

__global__ void csr_scan2(int* bsum, int nb)
{
  if (threadIdx.x == 0) {
    int run = 0;
    for (int i = 0; i < nb; ++i) { int v = bsum[i]; bsum[i] = run; run += v; }
  }
}

__global__ void csr_scan3(const int* __restrict__ loc, const int* __restrict__ bsum,
                          int* off, int* fillpos)
{
  int i = blockIdx.x * 256 + threadIdx.x;
  if (i < NN) {
    int o = loc[i] + bsum[i >> 8];
    off[i] = o;
    fillpos[i] = o;
  }
  if (i == 0) off[NN] = NE;
}

// fill CSR (elist = row id, tsl = timestamp) + median-bin candidate collection
__global__ void csr_fill(const int* __restrict__ row, const int* __restrict__ col,
                         const float* __restrict__ ts, const int* __restrict__ scal,
                         int* fillpos, int* __restrict__ elist, float* __restrict__ tsl,
                         float* cand1, float* cand2, int* ccnt)
{
  int e = blockIdx.x * 256 + threadIdx.x;
  if (e >= NE) return;
  int c = col[e], r = row[e];
  float t = ts[e];
  int slot = atomicAdd(fillpos + c, 1);
  elist[slot] = r;
  tsl[slot] = t;
  int b = ts_bin(t);
  if (b == scal[0]) {
    int s = atomicAdd(ccnt + 0, 1);
    if (s < CAND_CAP) cand1[s] = t;
  }
  if (b == scal[2]) {
    int s = atomicAdd(ccnt + 1, 1);
    if (s < CAND_CAP) cand2[s] = t;
  }
}

// per-node segment scan: nt=max ts, rec bits into elist, cnt_rec -> dis,
// col-side upd, and global nt min/max (replaces node_minmax/node_dis/atomicMax)
__global__ void node_scan(const int* __restrict__ off, int* __restrict__ elist,
                          const float* __restrict__ tsl, const int* __restrict__ scal,
                          float* __restrict__ nt, float* __restrict__ dis_r,
                          float* __restrict__ dis_h, unsigned char* __restrict__ upd,
                          int* scal_mm)
{
  int n = blockIdx.x * 256 + threadIdx.x;
  float mx = 0.f;
  bool valid = n < NN;
  if (valid) {
    int o0 = off[n], o1 = off[n + 1];
    float med = __int_as_float(scal[4]);
    int cr = 0;
    for (int j = o0; j < o1; ++j) {
      float t = tsl[j];
      mx = fmaxf(mx, t);
      if (t >= med) { cr++; elist[j] |= 0x80000000; }
    }
    nt[n] = mx;
    dis_r[n] = rsqrtf((float)cr + 1.f);
    dis_h[n] = rsqrtf((float)(o1 - o0 - cr) + 1.f);
    if (o1 > o0) upd[n] = 1;
  }
  float vmin = valid ? mx : 1e30f;
  float vmax = valid ? mx : -1e30f;
#pragma unroll
  for (int d = 1; d < 64; d <<= 1) {
    vmin = fminf(vmin, __shfl_xor(vmin, d));
    vmax = fmaxf(vmax, __shfl_xor(vmax, d));
  }
  __shared__ float smin[4], smax[4];
  int lane = threadIdx.x & 63, w = threadIdx.x >> 6;
  if (lane == 0) { smin[w] = vmin; smax[w] = vmax; }
  __syncthreads();
  if (threadIdx.x == 0) {
    float a = fminf(fminf(smin[0], smin[1]), fminf(smin[2], smin[3]));
    float b = fmaxf(fmaxf(smax[0], smax[1]), fmaxf(smax[2], smax[3]));
    atomicMin(scal_mm + 5, __float_as_int(a));
    atomicMax(scal_mm + 6, __float_as_int(b));
  }
}

// ---------------- GRU (f16 preacts in, f32 memory out) ---------------------
__device__ __forceinline__ float gru1(float rp, float zp, float ic, float hc, float mv) {
  float r = 1.f / (1.f + expf(-rp));
  float z = 1.f / (1.f + expf(-zp));
  float c = tanhf(ic + r * hc);
  return (1.f - z) * c + z * mv;
}

__global__ void gru_kernel(const _Float16* __restrict__ RZ, const _Float16* __restrict__ ICHC,
                           const float* __restrict__ mem, const unsigned char* __restrict__ upd,
                           float* __restrict__ out)
{
  int idx = blockIdx.x * 256 + threadIdx.x;
  if (idx >= NN * 32) return;
  int n = idx >> 5, q = (idx & 31) << 2;
  size_t p128 = (size_t)n * 128 + q;
  size_t p256 = (size_t)n * 256 + q;
  float4 mv = *(const float4*)(mem + p128);
  float4 o = mv;
  if (upd[n]) {
    f16x4 rp = *(const f16x4*)(RZ + p256);
    f16x4 zp = *(const f16x4*)(RZ + p256 + 128);
    f16x4 ic = *(const f16x4*)(ICHC + p256);
    f16x4 hc = *(const f16x4*)(ICHC + p256 + 128);
    o.x = gru1((float)rp[0], (float)zp[0], (float)ic[0], (float)hc[0], mv.x);
    o.y = gru1((float)rp[1], (float)zp[1], (float)ic[1], (float)hc[1], mv.y);
    o.z = gru1((float)rp[2], (float)zp[2], (float)ic[2], (float)hc[2], mv.z);
    o.w = gru1((float)rp[3], (float)zp[3], (float)ic[3], (float)hc[3], mv.w);
  }
  *(float4*)(out + p128) = o;
}

// ---------------- fused CSR gather + self-loop + softmax + LN --------------
// hl2: f16 [NN,256], cols 0:128 RECENT proj, 128:256 HISTORY proj.
// Wave-uniform control path scalarized; lanes do one 4B half2 load + 2 FMA/edge.
__global__ void gather_combine(const int* __restrict__ off, const int* __restrict__ elist,
                               const float* __restrict__ dis_r, const float* __restrict__ dis_h,
                               const _Float16* __restrict__ hl2,
                               const float* __restrict__ bgr, const float* __restrict__ bgh,
                               const float* __restrict__ g, const float* __restrict__ b,
                               _Float16* __restrict__ h2)
{
  int n = blockIdx.x * 4 + (threadIdx.x >> 6);
  if (n >= NN) return;
  int lane = threadIdx.x & 63;
  int o0 = __builtin_amdgcn_readfirstlane(off[n]);
  int o1 = __builtin_amdgcn_readfirstlane(off[n + 1]);
  float dnr = dis_r[n], dnh = dis_h[n];
  float arx = 0.f, ary = 0.f, ahx = 0.f, ahy = 0.f;
  int j = o0;
  for (; j + 1 < o1; j += 2) {
    int p0 = __builtin_amdgcn_readfirstlane(elist[j]);
    int p1 = __builtin_amdgcn_readfirstlane(elist[j + 1]);
    int r0 = p0 & 0x7fffffff, r1 = p1 & 0x7fffffff;
    int c0 = ((unsigned)p0) >> 31, c1 = ((unsigned)p1) >> 31;
    float d0 = c0 ? dis_r[r0] : dis_h[r0];
    float d1 = c1 ? dis_r[r1] : dis_h[r1];
    f16x2 v0 = *(const f16x2*)(hl2 + (size_t)r0 * 256 + ((c0 ^ 1) << 7) + (lane << 1));
    f16x2 v1 = *(const f16x2*)(hl2 + (size_t)r1 * 256 + ((c1 ^ 1) << 7) + (lane << 1));
    float k0 = d0 * (c0 ? dnr : dnh);
    float k1 = d1 * (c1 ? dnr : dnh);
    if (c0) { arx = fmaf(k0, (float)v0[0], arx); ary = fmaf(k0, (float)v0[1], ary); }
    else    { ahx = fmaf(k0, (float)v0[0], ahx); ahy = fmaf(k0, (float)v0[1], ahy); }
    if (c1) { arx = fmaf(k1, (float)v1[0], arx); ary = fmaf(k1, (float)v1[1], ary); }
    else    { ahx = fmaf(k1, (float)v1[0], ahx); ahy = fmaf(k1, (float)v1[1], ahy); }
  }
  if (j < o1) {
    int p0 = __builtin_amdgcn_readfirstlane(elist[j]);
    int r0 = p0 & 0x7fffffff;
    int c0 = ((unsigned)p0) >> 31;
    float d0 = c0 ? dis_r[r0] : dis_h[r0];
    f16x2 v0 = *(const f16x2*)(hl2 + (size_t)r0 * 256 + ((c0 ^ 1) << 7) + (lane << 1));
    float k0 = d0 * (c0 ? dnr : dnh);
    if (c0) { arx = fmaf(k0, (float)v0[0], arx); ary = fmaf(k0, (float)v0[1], ary); }
    else    { ahx = fmaf(k0, (float)v0[0], ahx); ahy = fmaf(k0, (float)v0[1], ahy); }
  }
  // self-loop + bias
  f16x2 lr = *(const f16x2*)(hl2 + (size_t)n * 256 + (lane << 1));
  f16x2 lh = *(const f16x2*)(hl2 + (size_t)n * 256 + 128 + (lane << 1));
  float2 br = *(const float2*)(bgr + (lane << 1));
  float2 bh = *(const float2*)(bgh + (lane << 1));
  float rx = arx + (float)lr[0] * dnr * dnr + br.x;
  float ry = ary + (float)lr[1] * dnr * dnr + br.y;
  float hx = ahx + (float)lh[0] * dnh * dnh + bh.x;
  float hy = ahy + (float)lh[1] * dnh * dnh + bh.y;
  // path softmax over per-path means
  float sa = rx + ry, sc = hx + hy;
#pragma unroll
  for (int d = 1; d < 64; d <<= 1) { sa += __shfl_xor(sa, d); sc += __shfl_xor(sc, d); }
  float m0 = sa * (1.f / 128.f), m1 = sc * (1.f / 128.f);
  float mx = fmaxf(m0, m1);
  float e0 = expf(m0 - mx), e1 = expf(m1 - mx);
  float inv = 1.f / (e0 + e1);
  float w0 = e0 * inv, w1 = e1 * inv;
  float yx = w0 * rx + w1 * hx;
  float yy = w0 * ry + w1 * hy;
  // LayerNorm
  float s = yx + yy;
#pragma unroll
  for (int d = 1; d < 64; d <<= 1) s += __shfl_xor(s, d);
  float mean = s * (1.f / 128.f);
  float dx = yx - mean, dy = yy - mean;
  float vv = dx * dx + dy * dy;
#pragma unroll
  for (int d = 1; d < 64; d <<= 1) vv += __shfl_xor(vv, d);
  float rstd = rsqrtf(vv * (1.f / 128.f) + 1e-5f);
  float2 gg = *(const float2*)(g + (lane << 1));
  float2 bb = *(const float2*)(b + (lane << 1));
  f16x2 o;
  o[0] = (_Float16)(dx * rstd * gg.x + bb.x);
  o[1] = (_Float16)(dy * rstd * gg.y + bb.y);
  *(f16x2*)(h2 + (size_t)n * NH + (lane << 1)) = o;
}

extern "C" void kernel_launch(void* const* d_in, const int* in_sizes, int n_in,
                              void* d_out, int out_size, void* d_ws, size_t ws_size,
                              hipStream_t stream)
{
  const float* x      = (const float*)d_in[0];
  const int*   ei     = (const int*)  d_in[1];
  const float* ts     = (const float*)d_in[2];
  const float* mem    = (const float*)d_in[3];
  const float* W_in   = (const float*)d_in[4];
  const float* b_in   = (const float*)d_in[5];
  const float* W_time = (const float*)d_in[6];
  const float* b_time = (const float*)d_in[7];
  const float* W_ih   = (const float*)d_in[8];
  const float* W_hh   = (const float*)d_in[9];
  const float* b_ih   = (const float*)d_in[10];
  const float* b_hh   = (const float*)d_in[11];
  const float* W_gr   = (const float*)d_in[12];
  const float* b_gr   = (const float*)d_in[13];
  const float* W_gh   = (const float*)d_in[14];
  const float* b_gh   = (const float*)d_in[15];
  const float* ln_pa_g= (const float*)d_in[16];
  const float* ln_pa_b= (const float*)d_in[17];
  const float* Wv     = (const float*)d_in[18];
  const float* bv     = (const float*)d_in[19];
  const float* Wo     = (const float*)d_in[20];
  const float* bo     = (const float*)d_in[21];
  const float* ln_at_g= (const float*)d_in[22];
  const float* ln_at_b= (const float*)d_in[23];
  const float* W1     = (const float*)d_in[24];
  const float* b1     = (const float*)d_in[25];
  const float* W2     = (const float*)d_in[26];
  const float* b2     = (const float*)d_in[27];

  const int* row = ei;
  const int* col = ei + NE;
  float* out_logits = (float*)d_out;
  float* out_mem    = (float*)d_out + NN * 2;

  float* ws = (float*)d_ws;
  // ---- workspace layout (offsets in floats), time-multiplexed ----
  // [0, 6.4M)      hb bf16 [NN,128]; after hl2-GEMM dead -> h2 f16 [NN,128]
  // [6.4M, 16M)    xb bf16 [NN,192]  (dead after EPI_H GEMM)
  // [6.4M, 19.2M)  rz f16 [NN,256]   (written after xb dead; dead after gru)
  // [6.4M, 12.8M)  rb bf16 [NN,128]  (written by ATTLN, after rz dead)
  // [19.2M, 32M)   ichc f16 [NN,256] (dead after gru)
  // [32M, 44.8M)   hl2 f16 [NN,256]  (written after gru)
  // [44.8M, 51.2M) memb bf16 [NN,128]
  unsigned short* hb   = (unsigned short*)(ws);
  _Float16* h2         = (_Float16*)(ws);
  unsigned short* xb   = (unsigned short*)(ws + 6400000);
  _Float16* rz         = (_Float16*)(ws + 6400000);
  unsigned short* rb   = (unsigned short*)(ws + 6400000);
  _Float16* ichc       = (_Float16*)(ws + 19200000);
  _Float16* hl2        = (_Float16*)(ws + 32000000);
  unsigned short* memb = (unsigned short*)(ws + 44800000);
  unsigned short* wb   = (unsigned short*)(ws + 51200000);   // 196608 shorts
  float* nt            = ws + 51350000;
  float* dis_r         = ws + 51450000;
  float* dis_h         = ws + 51550000;
  int* cnt_all         = (int*)(ws + 51650000);
  unsigned char* upd   = (unsigned char*)(ws + 51850000);    // NN bytes
  int* scal            = (int*)(ws + 51950000);
  float* batt          = ws + 51960000;
  float* cand1         = ws + 51970000;
  float* cand2         = ws + 51980000;
  int* ccnt            = (int*)(ws + 51990000);
  int* off             = (int*)(ws + 52100000);
  int* fillpos         = (int*)(ws + 52250000);
  int* loc             = (int*)(ws + 52400000);
  int* bsum            = (int*)(ws + 52550000);
  int* elist           = (int*)(ws + 52600000);              // [52.6M, 53.2M)
  float* tsl           = ws + 53200000;                      // [53.2M, 53.8M)
  int* ghist           = (int*)(ws + 53800000);              // 1024 ints

  unsigned short* wb_in = wb;
  unsigned short* wb_rz = wb + 24576;    // [256,256] = [W_ih[0:256] | W_hh[0:256]]
  unsigned short* wb_c  = wb + 90112;    // [256,128] = W_ih[256:384] ++ W_hh[256:384]
  unsigned short* wb_gr = wb + 122880;   // [256,128] = W_gr ++ W_gh contiguous
  unsigned short* wb_o  = wb + 172032;   // composed f16 W' = Wo@Wv
  unsigned short* wb_1  = wb + 188416;

  hipMemsetAsync(cnt_all, 0, NN * 4, stream);
  hipMemsetAsync(upd,     0, NN, stream);
  hipMemsetAsync(scal,    0, 16 * 4, stream);
  hipMemsetAsync(scal + 5,0x7f, 4, stream);
  hipMemsetAsync(ccnt,    0, 8, stream);
  hipMemsetAsync(ghist,   0, NBIN * 4, stream);

  const int eb  = (NE + 255) / 256;
  const int nb  = (NN + 255) / 256;
  dim3 blk(256);
  const unsigned gy = (NN + 127) / 128;

  // ---- edge statistics + CSR (atomic-minimized) ----
  edge_count<<<HBLK, 256, 0, stream>>>(row, col, ts, cnt_all, upd, ghist);
  scan_hist <<<1, 256, 0, stream>>>(ghist, scal);
  csr_scan1 <<<nb, 256, 0, stream>>>(cnt_all, loc, bsum);
  csr_scan2 <<<1, 64, 0, stream>>>(bsum, nb);
  csr_scan3 <<<nb, 256, 0, stream>>>(loc, bsum, off, fillpos);
  csr_fill  <<<eb, 256, 0, stream>>>(row, col, ts, scal, fillpos, elist, tsl,
                                     cand1, cand2, ccnt);
  select_med<<<1, 256, 0, stream>>>(cand1, cand2, ccnt, scal);
  node_scan <<<nb, 256, 0, stream>>>(off, elist, tsl, scal, nt, dis_r, dis_h,
                                     upd, scal);

  // bf16 conversions + attention weight composition
  conv_w     <<<768, 256, 0, stream>>>(W_in, W_ih, W_hh, W_gr, W_gh, Wv, Wo, W1, wb);
  compose_att<<<64, 256, 0, stream>>>(Wv, Wo, bv, bo, (_Float16*)wb_o, batt);
  conv_x     <<<75000, 256, 0, stream>>>(x, xb);

  // h = relu(x@W_in.T + b_in + nt_norm*W_time + b_time) + mem (bf16 hb),
  // side-writes memb = bf16(mem)
  mgemm<EPI_H, 2, false, false, false, false, 4><<<dim3(1, gy), blk, 0, stream>>>(
      xb, 192, nullptr, wb_in, 192, (float*)memb, 0, hb, NH, 192, 128,
      b_in, b_time, W_time, nt, mem, scal);
  // r,z preacts (f16): [h|mem] @ [W_ih[0:256]|W_hh[0:256]].T, 256 cols in one block
  mgemm<EPI_PLAIN, 3, true, true, false, false, 8><<<dim3(1, gy), blk, 0, stream>>>(
      hb, NH, memb, wb_rz, 256, nullptr, 0, (unsigned short*)rz, 256, 256, 256,
      b_ih, b_hh, nullptr, nullptr, nullptr, nullptr);
  // ic (x-block 0, A=h) and hc (x-block 1, A=mem) in one dual-A GEMM (f16 out)
  mgemm<EPI_PLAIN, 3, false, false, true, false, 4><<<dim3(2, gy), blk, 0, stream>>>(
      hb, NH, memb, wb_c, NH, nullptr, 0, (unsigned short*)ichc, 256, 128, 256,
      b_ih + 256, b_hh + 256, nullptr, nullptr, nullptr, nullptr);
  gru_kernel<<<(NN * 32) / 256, 256, 0, stream>>>(rz, ichc, mem, upd, out_mem);

  // both GCN projections in one GEMM: hl2 = h @ [W_gr; W_gh].T  [NN,256] f16
  mgemm<EPI_PLAIN, 3, false, false, false, false, 8><<<dim3(1, gy), blk, 0, stream>>>(
      hb, NH, nullptr, wb_gr, NH, nullptr, 0, (unsigned short*)hl2, 256, 128, 256,
      nullptr, nullptr, nullptr, nullptr, nullptr, nullptr);

  // fused gather + self-loop + path softmax + LN -> h2 (f16, aliases dead hb)
  gather_combine<<<(NN + 3) / 4, 256, 0, stream>>>(off, elist, dis_r, dis_h, hl2,
      b_gr, b_gh, ln_pa_g, ln_pa_b, h2);

  // attention + residual + LN fused into one f16 GEMM epilogue -> rb (bf16)
  mgemm<EPI_ATTLN, 2, false, false, false, true, 4><<<dim3(1, gy), blk, 0, stream>>>(
      (const unsigned short*)h2, NH, nullptr, wb_o, NH, nullptr, 0, rb, NH, 128, 128,
      batt, ln_at_b, ln_at_g, nullptr, (const float*)h2, scal);

  // classifier: relu(rb@W1.T+b1)@W2.T+b2 fused into one GEMM epilogue
  mgemm<EPI_HEAD, 0, false, false, false, false, 2><<<dim3(1, gy), blk, 0, stream>>>(
      rb, NH, nullptr, wb_1, NH, out_logits, 0, nullptr, 0, 128, 64,
      b1, b2, W2, nullptr, nullptr, nullptr);

  (void)in_sizes; (void)n_in; (void)out_size; (void)ws_size;
}

// Round 6
// 681.182 us; speedup vs baseline: 1.2752x; 1.0950x over previous
//
#include <hip/hip_runtime.h>

#define NN 100000
#define NE 600000
#define NF 166
#define NH 128
#define NNH 12800000

enum { EPI_PLAIN = 0, EPI_RELU = 2, EPI_H = 3, EPI_HEAD = 4, EPI_ATTLN = 5 };

typedef short bf16x8 __attribute__((ext_vector_type(8)));
typedef float f32x16 __attribute__((ext_vector_type(16)));
typedef _Float16 f16x2 __attribute__((ext_vector_type(2)));
typedef _Float16 f16x4 __attribute__((ext_vector_type(4)));
typedef _Float16 f16x8 __attribute__((ext_vector_type(8)));

__device__ __forceinline__ unsigned short f2bf(float f) {
  unsigned u = __float_as_uint(f);
  u += 0x7fffu + ((u >> 16) & 1u);
  return (unsigned short)(u >> 16);
}

__device__ __forceinline__ unsigned short f2h(float f) {
  return __builtin_bit_cast(unsigned short, (_Float16)f);
}

// async global->LDS, 16B per lane; LDS dest is wave-uniform base + lane*16
__device__ __forceinline__ void gl_lds16(const void* g, void* l) {
  __builtin_amdgcn_global_load_lds((__attribute__((address_space(1))) void*)(void*)g,
                                   (__attribute__((address_space(3))) void*)l, 16, 0, 0);
}

// ---------------- MFMA GEMM: C[n,m] = epi(sum_k A[n,k]*W[m,k]) -------------
// OUTK : 0 none, 1 f32 C, 2 bf16 Cb, 3 f16 Cb
// CONC : K=256, k>=128 sourced from A2 (concat-K, e.g. [h|mem])
// DUALA: blockIdx.x==1 uses A2 and bias2 (W rows already concatenated)
// F16  : A/W are fp16 (uses f16 MFMA); else bf16
// NT   : number of 32-col tiles per block (M = NT*32*gridDim.x)
template<int EPI, int OUTK, bool BIAS2, bool CONC, bool DUALA, bool F16, int NT>
__launch_bounds__(256)
__global__ void mgemm(const unsigned short* __restrict__ A, int lda,
                      const unsigned short* __restrict__ A2,
                      const unsigned short* __restrict__ W, int ldw,
                      float* __restrict__ C, int ldc,
                      unsigned short* __restrict__ Cb, int ldcb,
                      int K, int M,
                      const float* __restrict__ bias, const float* __restrict__ bias2,
                      const float* __restrict__ wtv, const float* __restrict__ ntv,
                      const float* __restrict__ mem, const int* __restrict__ scal)
{
  __shared__ unsigned short As[128 * 64];
  __shared__ unsigned short Bs[NT * 32 * 64];
  const int tid = threadIdx.x;
  const int wave = tid >> 6, lane = tid & 63;
  const int row0 = blockIdx.y * 128, col0 = blockIdx.x * NT * 32;
  if (DUALA && blockIdx.x) { A = A2; bias = bias2; }
  const int hi = lane >> 5, l5 = lane & 31, l3 = lane & 7;
  f32x16 acc[NT] = {};

  for (int k0 = 0; k0 < K; k0 += 64) {
    const unsigned short* Asrc = A;
    int kk = k0;
    if (CONC && k0 >= 128) { Asrc = A2; kk = k0 - 128; }
    __syncthreads();
#pragma unroll
    for (int q = 0; q < 4; ++q) {
      int id = q * 256 + tid;
      int r = id >> 3, cch = id & 7;
      // source-side XOR swizzle; LDS dest stays linear (required by global_load_lds)
      int sw = ((cch ^ (r & 7)) << 3);
      int gr = row0 + r; if (gr > NN - 1) gr = NN - 1;
      gl_lds16(Asrc + (size_t)gr * lda + kk + sw, &As[(q * 256 + wave * 64) * 8]);
    }
#pragma unroll
    for (int q = 0; q < NT; ++q) {
      int id = q * 256 + tid;
      int r = id >> 3, cch = id & 7;
      int sw = ((cch ^ (r & 7)) << 3);
      int gm = col0 + r; if (gm > M - 1) gm = M - 1;
      gl_lds16(W + (size_t)gm * ldw + k0 + sw, &Bs[(q * 256 + wave * 64) * 8]);
    }
    __syncthreads();   // compiler drains vmcnt before barrier -> LDS data visible
#pragma unroll
    for (int s = 0; s < 4; ++s) {
      int slot8 = (((s * 2 + hi) ^ l3) << 3);
      bf16x8 a = *(const bf16x8*)&As[(wave * 32 + l5) * 64 + slot8];
#pragma unroll
      for (int t = 0; t < NT; ++t) {
        bf16x8 b = *(const bf16x8*)&Bs[(t * 32 + l5) * 64 + slot8];
        if (F16)
          acc[t] = __builtin_amdgcn_mfma_f32_32x32x16_f16(
              __builtin_bit_cast(f16x8, a), __builtin_bit_cast(f16x8, b), acc[t], 0, 0, 0);
        else
          acc[t] = __builtin_amdgcn_mfma_f32_32x32x16_bf16(a, b, acc[t], 0, 0, 0);
      }
    }
  }

  float tmin = 0.f, tmax = 0.f;
  if (EPI == EPI_H) { tmin = __int_as_float(scal[5]); tmax = __int_as_float(scal[6]); }
  float bc[NT], wc[NT], b2c[NT];
#pragma unroll
  for (int t = 0; t < NT; ++t) {
    int gcol = col0 + t * 32 + l5;
    int bcol = DUALA ? (gcol & 127) : gcol;
    bc[t] = bias ? bias[bcol] : 0.f;
    if (BIAS2) bc[t] += bias2[gcol];
    if (EPI == EPI_H)     { bc[t] += bias2[gcol]; wc[t] = wtv[gcol]; }
    if (EPI == EPI_ATTLN) { wc[t] = wtv[gcol]; b2c[t] = bias2[gcol]; }
  }
#pragma unroll
  for (int rg = 0; rg < 16; ++rg) {
    int lr = (rg & 3) + 8 * (rg >> 2) + 4 * hi;
    int grow = row0 + wave * 32 + lr;
    if (grow >= NN) continue;
    float ntn = 0.f;
    if (EPI == EPI_H) {
      ntn = ntv[grow];
      if (tmax > tmin) ntn = (ntn - tmin) / (tmax - tmin + 1e-8f);
    }
    float hv[NT];
#pragma unroll
    for (int t = 0; t < NT; ++t) {
      float v = acc[t][rg] + bc[t];
      if (EPI == EPI_RELU || EPI == EPI_HEAD) v = fmaxf(v, 0.f);
      if (EPI == EPI_H) {
        v += ntn * wc[t];
        v = fmaxf(v, 0.f);
        float mv = mem[(size_t)grow * NH + (col0 + t * 32 + l5)];
        v += mv;
        // side-product: bf16 memory snapshot (replaces conv_mem kernel)
        ((unsigned short*)C)[(size_t)grow * NH + (col0 + t * 32 + l5)] = f2bf(mv);
      }
      hv[t] = v;
    }
    if (EPI == EPI_ATTLN) {
      // attended + residual, then LayerNorm across the row (cols live in 32-lane group)
      const _Float16* h2r = (const _Float16*)mem;
      float s = 0.f;
#pragma unroll
      for (int t = 0; t < NT; ++t) {
        hv[t] += (float)h2r[(size_t)grow * NH + (col0 + t * 32 + l5)];
        s += hv[t];
      }
#pragma unroll
      for (int d = 1; d < 32; d <<= 1) s += __shfl_xor(s, d);
      float mean = s * (1.f / 128.f);
      float var = 0.f;
#pragma unroll
      for (int t = 0; t < NT; ++t) { hv[t] -= mean; var += hv[t] * hv[t]; }
#pragma unroll
      for (int d = 1; d < 32; d <<= 1) var += __shfl_xor(var, d);
      float rstd = rsqrtf(var * (1.f / 128.f) + 1e-5f);
#pragma unroll
      for (int t = 0; t < NT; ++t) hv[t] = hv[t] * rstd * wc[t] + b2c[t];
    }
    if (EPI == EPI_HEAD) {
      // fused classifier head: logits = relu(h)@W2.T + b2  (wtv=W2 [2][64], bias2=b2)
      float p0 = hv[0] * wtv[l5]      + hv[1] * wtv[32 + l5];
      float p1 = hv[0] * wtv[64 + l5] + hv[1] * wtv[96 + l5];
#pragma unroll
      for (int d = 1; d < 32; d <<= 1) { p0 += __shfl_xor(p0, d); p1 += __shfl_xor(p1, d); }
      if (l5 == 0) {
        C[(size_t)grow * 2]     = p0 + bias2[0];
        C[(size_t)grow * 2 + 1] = p1 + bias2[1];
      }
    } else {
#pragma unroll
      for (int t = 0; t < NT; ++t) {
        int gcol = col0 + t * 32 + l5;
        if (OUTK == 1) C[(size_t)grow * ldc + gcol] = hv[t];
        if (OUTK == 2) Cb[(size_t)grow * ldcb + gcol] = f2bf(hv[t]);
        if (OUTK == 3) Cb[(size_t)grow * ldcb + gcol] = f2h(hv[t]);
      }
    }
  }
}

// ---------------- pre-convert kernels --------------------------------------
__global__ void conv_x(const float* __restrict__ x, unsigned short* __restrict__ xb)
{
  int i = blockIdx.x * 256 + threadIdx.x;
  if (i >= NN * 192) return;
  int n = i / 192, c = i - n * 192;
  xb[i] = (c < NF) ? f2bf(x[n * NF + c]) : (unsigned short)0;
}

// wb layout: [0,24576) W_in pad192 | [24576,90112) rz: row m = [W_ih[m]|W_hh[m]] (m<256)
//            [90112,122880) c: rows 0:128=W_ih[256:384], 128:256=W_hh[256:384]
//            [122880,155648) W_gr ++ W_gh | [155648,172032) Wv (unused)
//            [172032,188416) Wo (overwritten by composed f16 W') | [188416,196608) W1
__global__ void conv_w(const float* __restrict__ Wi, const float* __restrict__ Wih,
                       const float* __restrict__ Whh, const float* __restrict__ Wgr,
                       const float* __restrict__ Wgh, const float* __restrict__ Wv,
                       const float* __restrict__ Wo, const float* __restrict__ W1,
                       unsigned short* __restrict__ wb)
{
  int i = blockIdx.x * 256 + threadIdx.x;
  if (i >= 196608) return;
  float v;
  if (i < 24576)       { int r = i / 192, c = i - r * 192; v = (c < NF) ? Wi[r * NF + c] : 0.f; }
  else if (i < 90112)  { int j = i - 24576; int r = j >> 8, c = j & 255;
                         v = (c < 128) ? Wih[r * 128 + c] : Whh[r * 128 + (c - 128)]; }
  else if (i < 122880) { int j = i - 90112; int r = j >> 7, c = j & 127;
                         v = (r < 128) ? Wih[(256 + r) * 128 + c] : Whh[(128 + r) * 128 + c]; }
  else if (i < 139264) v = Wgr[i - 122880];
  else if (i < 155648) v = Wgh[i - 139264];
  else if (i < 172032) v = Wv[i - 155648];
  else if (i < 188416) v = Wo[i - 172032];
  else                 v = W1[i - 188416];
  wb[i] = f2bf(v);
}

// attended = h2 @ (Wo@Wv).T + (Wo@bv + bo): compose f16 W' and f32 b' on device
__global__ void compose_att(const float* __restrict__ Wv, const float* __restrict__ Wo,
                            const float* __restrict__ bv, const float* __restrict__ bo,
                            _Float16* __restrict__ wout, float* __restrict__ bout)
{
  int i = blockIdx.x * 256 + threadIdx.x;
  if (i >= 16384) return;
  int r = i >> 7, c = i & 127;
  float s = 0.f;
  for (int k = 0; k < 128; ++k) s = fmaf(Wo[r * 128 + k], Wv[k * 128 + c], s);
  wout[i] = (_Float16)s;
  if (c == 0) {
    float t = bo[r];
    for (int k = 0; k < 128; ++k) t = fmaf(Wo[r * 128 + k], bv[k], t);
    bout[r] = t;
  }
}

// ---------------- edge statistics ------------------------------------------
// 1024 value-uniform bins (ts ~ U[0,1)): ~586 edges/bin; monotone in t so
// order-statistic selection over bins is exact.
#define NBIN 1024
#define HBLK 256
__device__ __forceinline__ int ts_bin(float t) {
  int b = (int)(t * (float)NBIN);
  return b > NBIN - 1 ? NBIN - 1 : (b < 0 ? 0 : b);
}

// per-edge: ONE scattered global atomic (cnt_all) + one scattered byte store
// (upd row-side); LDS histogram flushed via global atomicAdd to ghist[1024]
__global__ void edge_count(const int* __restrict__ row, const int* __restrict__ col,
                           const float* __restrict__ ts,
                           int* __restrict__ cnt_all, unsigned char* __restrict__ upd,
                           int* __restrict__ ghist)
{
  __shared__ unsigned hist[NBIN];
  for (int i = threadIdx.x; i < NBIN; i += 256) hist[i] = 0;
  __syncthreads();
  for (int e = blockIdx.x * 256 + threadIdx.x; e < NE; e += 256 * HBLK) {
    int c = col[e];
    float t = ts[e];
    atomicAdd(cnt_all + c, 1);
    upd[row[e]] = 1;
    atomicAdd(&hist[ts_bin(t)], 1u);
  }
  __syncthreads();
  for (int i = threadIdx.x; i < NBIN; i += 256)
    atomicAdd(ghist + i, (int)hist[i]);
}

// tiny: 4KB read, 256-thread scan; find bins of order stats K1/K2
__global__ void scan_hist(const int* __restrict__ ghist, int* scal)
{
  __shared__ int s[256];
  int t = threadIdx.x;
  int4 mine = *(const int4*)(ghist + t * 4);   // 4 consecutive bins per thread
  int sum4 = mine.x + mine.y + mine.z + mine.w;
  s[t] = sum4;
  __syncthreads();
  for (int d = 1; d < 256; d <<= 1) {
    int add = (t >= d) ? s[t - d] : 0;
    __syncthreads();
    s[t] += add;
    __syncthreads();
  }
  int run = s[t] - sum4;
  const int K1 = 299999, K2 = 300000;
  int c[4] = { mine.x, mine.y, mine.z, mine.w };
#pragma unroll
  for (int k = 0; k < 4; ++k) {
    if (K1 >= run && K1 < run + c[k]) { scal[0] = t * 4 + k; scal[1] = run; }
    if (K2 >= run && K2 < run + c[k]) { scal[2] = t * 4 + k; scal[3] = run; }
    run += c[k];
  }
}

#define CAND_CAP 4096
// exact rank-select within candidate bins, candidates staged in LDS
// (global-scatter variant was a 98us single-CU latency-bound kernel:
//  ~1400 serial ~500cy HBM reads/thread; LDS broadcast reads are ~2cy)
__global__ void select_med(const float* __restrict__ c1, const float* __restrict__ c2,
                           const int* __restrict__ ccnt, int* scal)
{
  __shared__ float buf[CAND_CAP];
  __shared__ float res[2];
  for (int which = 0; which < 2; ++which) {
    const float* c = which ? c2 : c1;
    int m = ccnt[which]; if (m > CAND_CAP) m = CAND_CAP;
    for (int i = threadIdx.x; i < m; i += 256) buf[i] = c[i];
    __syncthreads();
    int rank = which ? (300000 - scal[3]) : (299999 - scal[1]);
    for (int i = threadIdx.x; i < m; i += 256) {
      float v = buf[i];
      int less = 0, eq = 0;
      for (int j = 0; j < m; ++j) { float w = buf[j]; less += (w < v); eq += (w == v); }
      if (less <= rank && rank < less + eq) res[which] = v;
    }
    __syncthreads();
  }
  if (threadIdx.x == 0)
    ((float*)scal)[4] = 0.5f * (res[0] + res[1]);
}

// ---------------- CSR build ------------------------------------------------
__global__ void csr_scan1(const int* __restrict__ cnt, int* loc, int* bsum)
{
  __shared__ int s[256];
  int t = threadIdx.x;
  int i = blockIdx.x * 256 + t;
  int v = (i < NN) ? cnt[i] : 0;
  s[t] = v;
  __syncthreads();
  for (int d = 1; d < 256; d <<= 1) {
    int add = (t >= d) ? s[t - d] : 0;
    __syncthreads();
    s[t] += add;
    __syncthreads();
  }
  if (i < NN) loc[i] = s[t] - v;
  if (t == 255) bsum[blockIdx.x] = s[255];
}

// parallel exclusive scan of block sums (<=512 blocks; 2 elems/thread)
__global__ void csr_scan2(int* bsum, int nb)
{
  __shared__ int s[256];
  int t = threadIdx.x;
  int i0 = 2 * t, i1 = 2 * t + 1;
  int v0 = (i0 < nb) ? bsum[i0] : 0;
  int v1 = (i1 < nb) ? bsum[i1] : 0;
  int sum = v0 + v1;
  s[t] = sum;
  __syncthreads();
  for (int d = 1; d < 256; d <<= 1) {
    int add = (t >= d) ? s[t - d] : 0;
    __syncthreads();
    s[t] += add;
    __syncthreads();
  }
  int excl = s[t] - sum;
  if (i0 < nb) bsum[i0] = excl;
  if (i1 < nb) bsum[i1] = excl + v0;
}

__global__ void csr_scan3(const int* __restrict__ loc, const int* __restrict__ bsum,
                          int* off, int* fillpos)
{
  int i = blockIdx.x * 256 + threadIdx.x;
  if (i < NN) {
    int o = loc[i] + bsum[i >> 8];
    off[i] = o;
    fillpos[i] = o;
  }
  if (i == 0) off[NN] = NE;
}

// fill CSR (elist = row id, tsl = timestamp) + median-bin candidate collection
__global__ void csr_fill(const int* __restrict__ row, const int* __restrict__ col,
                         const float* __restrict__ ts, const int* __restrict__ scal,
                         int* fillpos, int* __restrict__ elist, float* __restrict__ tsl,
                         float* cand1, float* cand2, int* ccnt)
{
  int e = blockIdx.x * 256 + threadIdx.x;
  if (e >= NE) return;
  int c = col[e], r = row[e];
  float t = ts[e];
  int slot = atomicAdd(fillpos + c, 1);
  elist[slot] = r;
  tsl[slot] = t;
  int b = ts_bin(t);
  if (b == scal[0]) {
    int s = atomicAdd(ccnt + 0, 1);
    if (s < CAND_CAP) cand1[s] = t;
  }
  if (b == scal[2]) {
    int s = atomicAdd(ccnt + 1, 1);
    if (s < CAND_CAP) cand2[s] = t;
  }
}

// per-node segment scan: nt=max ts, rec bits into elist, cnt_rec -> dis,
// col-side upd, and global nt min/max
__global__ void node_scan(const int* __restrict__ off, int* __restrict__ elist,
                          const float* __restrict__ tsl, const int* __restrict__ scal,
                          float* __restrict__ nt, float* __restrict__ dis_r,
                          float* __restrict__ dis_h, unsigned char* __restrict__ upd,
                          int* scal_mm)
{
  int n = blockIdx.x * 256 + threadIdx.x;
  float mx = 0.f;
  bool valid = n < NN;
  if (valid) {
    int o0 = off[n], o1 = off[n + 1];
    float med = __int_as_float(scal[4]);
    int cr = 0;
    for (int j = o0; j < o1; ++j) {
      float t = tsl[j];
      mx = fmaxf(mx, t);
      if (t >= med) { cr++; elist[j] |= 0x80000000; }
    }
    nt[n] = mx;
    dis_r[n] = rsqrtf((float)cr + 1.f);
    dis_h[n] = rsqrtf((float)(o1 - o0 - cr) + 1.f);
    if (o1 > o0) upd[n] = 1;
  }
  float vmin = valid ? mx : 1e30f;
  float vmax = valid ? mx : -1e30f;
#pragma unroll
  for (int d = 1; d < 64; d <<= 1) {
    vmin = fminf(vmin, __shfl_xor(vmin, d));
    vmax = fmaxf(vmax, __shfl_xor(vmax, d));
  }
  __shared__ float smin[4], smax[4];
  int lane = threadIdx.x & 63, w = threadIdx.x >> 6;
  if (lane == 0) { smin[w] = vmin; smax[w] = vmax; }
  __syncthreads();
  if (threadIdx.x == 0) {
    float a = fminf(fminf(smin[0], smin[1]), fminf(smin[2], smin[3]));
    float b = fmaxf(fmaxf(smax[0], smax[1]), fmaxf(smax[2], smax[3]));
    atomicMin(scal_mm + 5, __float_as_int(a));
    atomicMax(scal_mm + 6, __float_as_int(b));
  }
}

// ---------------- GRU (f16 preacts in, f32 memory out) ---------------------
__device__ __forceinline__ float gru1(float rp, float zp, float ic, float hc, float mv) {
  float r = 1.f / (1.f + expf(-rp));
  float z = 1.f / (1.f + expf(-zp));
  float c = tanhf(ic + r * hc);
  return (1.f - z) * c + z * mv;
}

__global__ void gru_kernel(const _Float16* __restrict__ RZ, const _Float16* __restrict__ ICHC,
                           const float* __restrict__ mem, const unsigned char* __restrict__ upd,
                           float* __restrict__ out)
{
  int idx = blockIdx.x * 256 + threadIdx.x;
  if (idx >= NN * 32) return;
  int n = idx >> 5, q = (idx & 31) << 2;
  size_t p128 = (size_t)n * 128 + q;
  size_t p256 = (size_t)n * 256 + q;
  float4 mv = *(const float4*)(mem + p128);
  float4 o = mv;
  if (upd[n]) {
    f16x4 rp = *(const f16x4*)(RZ + p256);
    f16x4 zp = *(const f16x4*)(RZ + p256 + 128);
    f16x4 ic = *(const f16x4*)(ICHC + p256);
    f16x4 hc = *(const f16x4*)(ICHC + p256 + 128);
    o.x = gru1((float)rp[0], (float)zp[0], (float)ic[0], (float)hc[0], mv.x);
    o.y = gru1((float)rp[1], (float)zp[1], (float)ic[1], (float)hc[1], mv.y);
    o.z = gru1((float)rp[2], (float)zp[2], (float)ic[2], (float)hc[2], mv.z);
    o.w = gru1((float)rp[3], (float)zp[3], (float)ic[3], (float)hc[3], mv.w);
  }
  *(float4*)(out + p128) = o;
}

// ---------------- fused CSR gather + self-loop + softmax + LN --------------
// hl2: f16 [NN,256], cols 0:128 RECENT proj, 128:256 HISTORY proj.
// Wave-uniform control path scalarized; lanes do one 4B half2 load + 2 FMA/edge.
__global__ void gather_combine(const int* __restrict__ off, const int* __restrict__ elist,
                               const float* __restrict__ dis_r, const float* __restrict__ dis_h,
                               const _Float16* __restrict__ hl2,
                               const float* __restrict__ bgr, const float* __restrict__ bgh,
                               const float* __restrict__ g, const float* __restrict__ b,
                               _Float16* __restrict__ h2)
{
  int n = blockIdx.x * 4 + (threadIdx.x >> 6);
  if (n >= NN) return;
  int lane = threadIdx.x & 63;
  int o0 = __builtin_amdgcn_readfirstlane(off[n]);
  int o1 = __builtin_amdgcn_readfirstlane(off[n + 1]);
  float dnr = dis_r[n], dnh = dis_h[n];
  float arx = 0.f, ary = 0.f, ahx = 0.f, ahy = 0.f;
  int j = o0;
  for (; j + 1 < o1; j += 2) {
    int p0 = __builtin_amdgcn_readfirstlane(elist[j]);
    int p1 = __builtin_amdgcn_readfirstlane(elist[j + 1]);
    int r0 = p0 & 0x7fffffff, r1 = p1 & 0x7fffffff;
    int c0 = ((unsigned)p0) >> 31, c1 = ((unsigned)p1) >> 31;
    float d0 = c0 ? dis_r[r0] : dis_h[r0];
    float d1 = c1 ? dis_r[r1] : dis_h[r1];
    f16x2 v0 = *(const f16x2*)(hl2 + (size_t)r0 * 256 + ((c0 ^ 1) << 7) + (lane << 1));
    f16x2 v1 = *(const f16x2*)(hl2 + (size_t)r1 * 256 + ((c1 ^ 1) << 7) + (lane << 1));
    float k0 = d0 * (c0 ? dnr : dnh);
    float k1 = d1 * (c1 ? dnr : dnh);
    if (c0) { arx = fmaf(k0, (float)v0[0], arx); ary = fmaf(k0, (float)v0[1], ary); }
    else    { ahx = fmaf(k0, (float)v0[0], ahx); ahy = fmaf(k0, (float)v0[1], ahy); }
    if (c1) { arx = fmaf(k1, (float)v1[0], arx); ary = fmaf(k1, (float)v1[1], ary); }
    else    { ahx = fmaf(k1, (float)v1[0], ahx); ahy = fmaf(k1, (float)v1[1], ahy); }
  }
  if (j < o1) {
    int p0 = __builtin_amdgcn_readfirstlane(elist[j]);
    int r0 = p0 & 0x7fffffff;
    int c0 = ((unsigned)p0) >> 31;
    float d0 = c0 ? dis_r[r0] : dis_h[r0];
    f16x2 v0 = *(const f16x2*)(hl2 + (size_t)r0 * 256 + ((c0 ^ 1) << 7) + (lane << 1));
    float k0 = d0 * (c0 ? dnr : dnh);
    if (c0) { arx = fmaf(k0, (float)v0[0], arx); ary = fmaf(k0, (float)v0[1], ary); }
    else    { ahx = fmaf(k0, (float)v0[0], ahx); ahy = fmaf(k0, (float)v0[1], ahy); }
  }
  // self-loop + bias
  f16x2 lr = *(const f16x2*)(hl2 + (size_t)n * 256 + (lane << 1));
  f16x2 lh = *(const f16x2*)(hl2 + (size_t)n * 256 + 128 + (lane << 1));
  float2 br = *(const float2*)(bgr + (lane << 1));
  float2 bh = *(const float2*)(bgh + (lane << 1));
  float rx = arx + (float)lr[0] * dnr * dnr + br.x;
  float ry = ary + (float)lr[1] * dnr * dnr + br.y;
  float hx = ahx + (float)lh[0] * dnh * dnh + bh.x;
  float hy = ahy + (float)lh[1] * dnh * dnh + bh.y;
  // path softmax over per-path means
  float sa = rx + ry, sc = hx + hy;
#pragma unroll
  for (int d = 1; d < 64; d <<= 1) { sa += __shfl_xor(sa, d); sc += __shfl_xor(sc, d); }
  float m0 = sa * (1.f / 128.f), m1 = sc * (1.f / 128.f);
  float mx = fmaxf(m0, m1);
  float e0 = expf(m0 - mx), e1 = expf(m1 - mx);
  float inv = 1.f / (e0 + e1);
  float w0 = e0 * inv, w1 = e1 * inv;
  float yx = w0 * rx + w1 * hx;
  float yy = w0 * ry + w1 * hy;
  // LayerNorm
  float s = yx + yy;
#pragma unroll
  for (int d = 1; d < 64; d <<= 1) s += __shfl_xor(s, d);
  float mean = s * (1.f / 128.f);
  float dx = yx - mean, dy = yy - mean;
  float vv = dx * dx + dy * dy;
#pragma unroll
  for (int d = 1; d < 64; d <<= 1) vv += __shfl_xor(vv, d);
  float rstd = rsqrtf(vv * (1.f / 128.f) + 1e-5f);
  float2 gg = *(const float2*)(g + (lane << 1));
  float2 bb = *(const float2*)(b + (lane << 1));
  f16x2 o;
  o[0] = (_Float16)(dx * rstd * gg.x + bb.x);
  o[1] = (_Float16)(dy * rstd * gg.y + bb.y);
  *(f16x2*)(h2 + (size_t)n * NH + (lane << 1)) = o;
}

extern "C" void kernel_launch(void* const* d_in, const int* in_sizes, int n_in,
                              void* d_out, int out_size, void* d_ws, size_t ws_size,
                              hipStream_t stream)
{
  const float* x      = (const float*)d_in[0];
  const int*   ei     = (const int*)  d_in[1];
  const float* ts     = (const float*)d_in[2];
  const float* mem    = (const float*)d_in[3];
  const float* W_in   = (const float*)d_in[4];
  const float* b_in   = (const float*)d_in[5];
  const float* W_time = (const float*)d_in[6];
  const float* b_time = (const float*)d_in[7];
  const float* W_ih   = (const float*)d_in[8];
  const float* W_hh   = (const float*)d_in[9];
  const float* b_ih   = (const float*)d_in[10];
  const float* b_hh   = (const float*)d_in[11];
  const float* W_gr   = (const float*)d_in[12];
  const float* b_gr   = (const float*)d_in[13];
  const float* W_gh   = (const float*)d_in[14];
  const float* b_gh   = (const float*)d_in[15];
  const float* ln_pa_g= (const float*)d_in[16];
  const float* ln_pa_b= (const float*)d_in[17];
  const float* Wv     = (const float*)d_in[18];
  const float* bv     = (const float*)d_in[19];
  const float* Wo     = (const float*)d_in[20];
  const float* bo     = (const float*)d_in[21];
  const float* ln_at_g= (const float*)d_in[22];
  const float* ln_at_b= (const float*)d_in[23];
  const float* W1     = (const float*)d_in[24];
  const float* b1     = (const float*)d_in[25];
  const float* W2     = (const float*)d_in[26];
  const float* b2     = (const float*)d_in[27];

  const int* row = ei;
  const int* col = ei + NE;
  float* out_logits = (float*)d_out;
  float* out_mem    = (float*)d_out + NN * 2;

  float* ws = (float*)d_ws;
  // ---- workspace layout (offsets in floats), time-multiplexed ----
  unsigned short* hb   = (unsigned short*)(ws);
  _Float16* h2         = (_Float16*)(ws);
  unsigned short* xb   = (unsigned short*)(ws + 6400000);
  _Float16* rz         = (_Float16*)(ws + 6400000);
  unsigned short* rb   = (unsigned short*)(ws + 6400000);
  _Float16* ichc       = (_Float16*)(ws + 19200000);
  _Float16* hl2        = (_Float16*)(ws + 32000000);
  unsigned short* memb = (unsigned short*)(ws + 44800000);
  unsigned short* wb   = (unsigned short*)(ws + 51200000);   // 196608 shorts
  float* nt            = ws + 51350000;
  float* dis_r         = ws + 51450000;
  float* dis_h         = ws + 51550000;
  int* cnt_all         = (int*)(ws + 51650000);
  unsigned char* upd   = (unsigned char*)(ws + 51850000);    // NN bytes
  int* scal            = (int*)(ws + 51950000);
  float* batt          = ws + 51960000;
  float* cand1         = ws + 51970000;
  float* cand2         = ws + 51980000;
  int* ccnt            = (int*)(ws + 51990000);
  int* off             = (int*)(ws + 52100000);
  int* fillpos         = (int*)(ws + 52250000);
  int* loc             = (int*)(ws + 52400000);
  int* bsum            = (int*)(ws + 52550000);
  int* elist           = (int*)(ws + 52600000);              // [52.6M, 53.2M)
  float* tsl           = ws + 53200000;                      // [53.2M, 53.8M)
  int* ghist           = (int*)(ws + 53800000);              // 1024 ints

  unsigned short* wb_in = wb;
  unsigned short* wb_rz = wb + 24576;    // [256,256] = [W_ih[0:256] | W_hh[0:256]]
  unsigned short* wb_c  = wb + 90112;    // [256,128] = W_ih[256:384] ++ W_hh[256:384]
  unsigned short* wb_gr = wb + 122880;   // [256,128] = W_gr ++ W_gh contiguous
  unsigned short* wb_o  = wb + 172032;   // composed f16 W' = Wo@Wv
  unsigned short* wb_1  = wb + 188416;

  hipMemsetAsync(cnt_all, 0, NN * 4, stream);
  hipMemsetAsync(upd,     0, NN, stream);
  hipMemsetAsync(scal,    0, 16 * 4, stream);
  hipMemsetAsync(scal + 5,0x7f, 4, stream);
  hipMemsetAsync(ccnt,    0, 8, stream);
  hipMemsetAsync(ghist,   0, NBIN * 4, stream);

  const int eb  = (NE + 255) / 256;
  const int nb  = (NN + 255) / 256;
  dim3 blk(256);
  const unsigned gy = (NN + 127) / 128;

  // ---- edge statistics + CSR (atomic-minimized) ----
  edge_count<<<HBLK, 256, 0, stream>>>(row, col, ts, cnt_all, upd, ghist);
  scan_hist <<<1, 256, 0, stream>>>(ghist, scal);
  csr_scan1 <<<nb, 256, 0, stream>>>(cnt_all, loc, bsum);
  csr_scan2 <<<1, 256, 0, stream>>>(bsum, nb);
  csr_scan3 <<<nb, 256, 0, stream>>>(loc, bsum, off, fillpos);
  csr_fill  <<<eb, 256, 0, stream>>>(row, col, ts, scal, fillpos, elist, tsl,
                                     cand1, cand2, ccnt);
  select_med<<<1, 256, 0, stream>>>(cand1, cand2, ccnt, scal);
  node_scan <<<nb, 256, 0, stream>>>(off, elist, tsl, scal, nt, dis_r, dis_h,
                                     upd, scal);

  // bf16 conversions + attention weight composition
  conv_w     <<<768, 256, 0, stream>>>(W_in, W_ih, W_hh, W_gr, W_gh, Wv, Wo, W1, wb);
  compose_att<<<64, 256, 0, stream>>>(Wv, Wo, bv, bo, (_Float16*)wb_o, batt);
  conv_x     <<<75000, 256, 0, stream>>>(x, xb);

  // h = relu(x@W_in.T + b_in + nt_norm*W_time + b_time) + mem (bf16 hb),
  // side-writes memb = bf16(mem)
  mgemm<EPI_H, 2, false, false, false, false, 4><<<dim3(1, gy), blk, 0, stream>>>(
      xb, 192, nullptr, wb_in, 192, (float*)memb, 0, hb, NH, 192, 128,
      b_in, b_time, W_time, nt, mem, scal);
  // r,z preacts (f16): [h|mem] @ [W_ih[0:256]|W_hh[0:256]].T, 256 cols in one block
  mgemm<EPI_PLAIN, 3, true, true, false, false, 8><<<dim3(1, gy), blk, 0, stream>>>(
      hb, NH, memb, wb_rz, 256, nullptr, 0, (unsigned short*)rz, 256, 256, 256,
      b_ih, b_hh, nullptr, nullptr, nullptr, nullptr);
  // ic (x-block 0, A=h) and hc (x-block 1, A=mem) in one dual-A GEMM (f16 out)
  mgemm<EPI_PLAIN, 3, false, false, true, false, 4><<<dim3(2, gy), blk, 0, stream>>>(
      hb, NH, memb, wb_c, NH, nullptr, 0, (unsigned short*)ichc, 256, 128, 256,
      b_ih + 256, b_hh + 256, nullptr, nullptr, nullptr, nullptr);
  gru_kernel<<<(NN * 32) / 256, 256, 0, stream>>>(rz, ichc, mem, upd, out_mem);

  // both GCN projections in one GEMM: hl2 = h @ [W_gr; W_gh].T  [NN,256] f16
  mgemm<EPI_PLAIN, 3, false, false, false, false, 8><<<dim3(1, gy), blk, 0, stream>>>(
      hb, NH, nullptr, wb_gr, NH, nullptr, 0, (unsigned short*)hl2, 256, 128, 256,
      nullptr, nullptr, nullptr, nullptr, nullptr, nullptr);

  // fused gather + self-loop + path softmax + LN -> h2 (f16, aliases dead hb)
  gather_combine<<<(NN + 3) / 4, 256, 0, stream>>>(off, elist, dis_r, dis_h, hl2,
      b_gr, b_gh, ln_pa_g, ln_pa_b, h2);

  // attention + residual + LN fused into one f16 GEMM epilogue -> rb (bf16)
  mgemm<EPI_ATTLN, 2, false, false, false, true, 4><<<dim3(1, gy), blk, 0, stream>>>(
      (const unsigned short*)h2, NH, nullptr, wb_o, NH, nullptr, 0, rb, NH, 128, 128,
      batt, ln_at_b, ln_at_g, nullptr, (const float*)h2, scal);

  // classifier: relu(rb@W1.T+b1)@W2.T+b2 fused into one GEMM epilogue
  mgemm<EPI_HEAD, 0, false, false, false, false, 2><<<dim3(1, gy), blk, 0, stream>>>(
      rb, NH, nullptr, wb_1, NH, out_logits, 0, nullptr, 0, 128, 64,
      b1, b2, W2, nullptr, nullptr, nullptr);

  (void)in_sizes; (void)n_in; (void)out_size; (void)ws_size;
}